// Round 1
// baseline (2739.070 us; speedup 1.0000x reference)
//
#include <hip/hip_runtime.h>
#include <math.h>

#define BD 8
#define DD 1024
#define EE 256
#define HH 8
#define HDD 32
#define NBITS 11

// ---------------- q_scale: FiLM gain from neighbor mean ----------------
__global__ __launch_bounds__(256) void k_qscale(const float* __restrict__ x,
                                                const float* __restrict__ film_alpha,
                                                const float* __restrict__ film_a,
                                                float* __restrict__ qscale) {
  __shared__ float red[256];
  int b = blockIdx.x, t = threadIdx.x;
  float s = 0.f;
  #pragma unroll
  for (int i = 0; i < 4; i++) s += x[b * DD + t + i * 256];
  red[t] = s; __syncthreads();
  for (int off = 128; off > 0; off >>= 1) {
    if (t < off) red[t] += red[t + off];
    __syncthreads();
  }
  float total = red[0];
  float ta = tanhf(film_alpha[0]);
  float fa = film_a[0];
  #pragma unroll
  for (int i = 0; i < 4; i++) {
    int d = t + i * 256;
    float xn = (total - x[b * DD + d]) / 1023.0f;
    float qs = 1.0f + ta * tanhf(fa * xn);
    qs = fminf(fmaxf(qs, 0.7f), 1.3f);
    qscale[b * DD + d] = qs;
  }
}

// ---------------- pos = feature_embed + codes @ binary_w.T ----------------
__global__ __launch_bounds__(256) void k_pos(const float* __restrict__ fe,
                                             const float* __restrict__ binary_w,
                                             float* __restrict__ pos) {
  int d = blockIdx.x, e = threadIdx.x;
  float s = fe[d * EE + e];
  int code = d + 1;
  #pragma unroll
  for (int bit = 0; bit < NBITS; bit++) {
    float cb = (float)((code >> (NBITS - 1 - bit)) & 1) - 0.5f;
    s += cb * binary_w[e * NBITS + bit];
  }
  pos[d * EE + e] = s;
}

// ---------------- kv = x*value_w + value_b + pos ; h = pos ----------------
__global__ __launch_bounds__(256) void k_kvh(const float* __restrict__ x,
                                             const float* __restrict__ value_w,
                                             const float* __restrict__ value_b,
                                             const float* __restrict__ pos,
                                             float* __restrict__ kv,
                                             float* __restrict__ h) {
  int idx = blockIdx.x * 256 + threadIdx.x;   // over B*D*E = 2M
  int e = idx & (EE - 1);
  int d = (idx >> 8) & (DD - 1);
  int b = idx >> 18;
  float p = pos[(idx & (DD * EE - 1))];
  kv[idx] = x[b * DD + d] * value_w[e] + value_b[e] + p;
  h[idx] = p;
}

// ---------------- generic tiled fp32 GEMM: C[M,N] = A[M,K] @ W[N,K]^T ----------------
// EPI 0: C = acc
// EPI 1: C = acc * aux1[row]
// EPI 2: C = gelu_exact(acc + aux1[col])
// EPI 3: C[row,col] += aux2[col] * (acc + aux1[col])
template <int EPI>
__global__ __launch_bounds__(256) void gemm_k(const float* __restrict__ A,
                                              const float* __restrict__ W,
                                              float* __restrict__ C,
                                              int M, int N, int K,
                                              const float* __restrict__ aux1,
                                              const float* __restrict__ aux2) {
  __shared__ float As[64][33];
  __shared__ float Ws[64][33];
  int bx = blockIdx.x, by = blockIdx.y;
  int tid = threadIdx.x;
  int tx = tid & 15, ty = tid >> 4;
  float acc[4][4] = {};
  const float* Ab = A + (size_t)(by * 64) * K;
  const float* Wb = W + (size_t)(bx * 64) * K;
  for (int k0 = 0; k0 < K; k0 += 32) {
    #pragma unroll
    for (int i = 0; i < 8; i++) {
      int l = tid + i * 256;
      int r = l >> 5, c = l & 31;
      As[r][c] = Ab[(size_t)r * K + k0 + c];
      Ws[r][c] = Wb[(size_t)r * K + k0 + c];
    }
    __syncthreads();
    #pragma unroll
    for (int kk = 0; kk < 32; kk++) {
      float a0 = As[ty * 4 + 0][kk];
      float a1 = As[ty * 4 + 1][kk];
      float a2 = As[ty * 4 + 2][kk];
      float a3 = As[ty * 4 + 3][kk];
      float b0 = Ws[tx * 4 + 0][kk];
      float b1 = Ws[tx * 4 + 1][kk];
      float b2 = Ws[tx * 4 + 2][kk];
      float b3 = Ws[tx * 4 + 3][kk];
      acc[0][0] += a0 * b0; acc[0][1] += a0 * b1; acc[0][2] += a0 * b2; acc[0][3] += a0 * b3;
      acc[1][0] += a1 * b0; acc[1][1] += a1 * b1; acc[1][2] += a1 * b2; acc[1][3] += a1 * b3;
      acc[2][0] += a2 * b0; acc[2][1] += a2 * b1; acc[2][2] += a2 * b2; acc[2][3] += a2 * b3;
      acc[3][0] += a3 * b0; acc[3][1] += a3 * b1; acc[3][2] += a3 * b2; acc[3][3] += a3 * b3;
    }
    __syncthreads();
  }
  #pragma unroll
  for (int i = 0; i < 4; i++) {
    int row = by * 64 + ty * 4 + i;
    #pragma unroll
    for (int j = 0; j < 4; j++) {
      int col = bx * 64 + tx * 4 + j;
      float v = acc[i][j];
      size_t idx = (size_t)row * N + col;
      if (EPI == 0) {
        C[idx] = v;
      } else if (EPI == 1) {
        C[idx] = v * aux1[row];
      } else if (EPI == 2) {
        v += aux1[col];
        C[idx] = 0.5f * v * (1.0f + erff(v * 0.70710678118654752f));
      } else if (EPI == 3) {
        v += aux1[col];
        C[idx] += aux2[col] * v;
      }
    }
  }
}

// ---------------- fused attention: one wave per (b,h,q-row) ----------------
__global__ __launch_bounds__(256) void attn_k(const float* __restrict__ q,
                                              const float* __restrict__ Km,
                                              const float* __restrict__ Vm,
                                              const float* __restrict__ gamma,
                                              const float* __restrict__ strength_p,
                                              float* __restrict__ h) {
  __shared__ float s_p[4][DD];
  int w = threadIdx.x >> 6, lane = threadIdx.x & 63;
  int r = blockIdx.x * 4 + w;                // 0 .. B*H*D-1
  int b = r >> 13;                           // / (H*D)
  int hh = (r >> 10) & (HH - 1);
  int d = r & (DD - 1);
  float str = fmaxf(strength_p[0], 0.0f);
  float slope = exp2f(-(float)hh / (float)HH);
  const float* qrow = q + ((size_t)(b * DD + d)) * EE + hh * HDD;
  float qr[HDD];
  #pragma unroll
  for (int e = 0; e < HDD; e++) qr[e] = qrow[e] * 0.17677669529663687f; // 1/sqrt(32)

  // pass 1: scores + online max
  float sc[16];
  float m = -1e30f;
  for (int jj = 0; jj < 16; jj++) {
    int j = jj * 64 + lane;
    const float* krow = Km + ((size_t)(b * DD + j)) * EE + hh * HDD;
    float s = 0.f;
    #pragma unroll
    for (int e = 0; e < HDD; e++) s += qr[e] * krow[e];
    s += (j == d) ? -1e30f : -str * slope * fabsf((float)(d - j));
    sc[jj] = s;
    m = fmaxf(m, s);
  }
  #pragma unroll
  for (int off = 32; off; off >>= 1) m = fmaxf(m, __shfl_xor(m, off));
  float l = 0.f;
  #pragma unroll
  for (int jj = 0; jj < 16; jj++) {
    float p = expf(sc[jj] - m);
    l += p;
    s_p[w][jj * 64 + lane] = p;
  }
  #pragma unroll
  for (int off = 32; off; off >>= 1) l += __shfl_xor(l, off);
  __syncthreads();

  // pass 2: attn = P @ V, lane e owns dim (lane&31), half-split over keys
  int e = lane & 31;
  int jbase = (lane >> 5) * 512;
  const float* vcol = Vm + ((size_t)(b * DD + jbase)) * EE + hh * HDD + e;
  float acc = 0.f;
  for (int j2 = 0; j2 < 512; j2++) acc += s_p[w][jbase + j2] * vcol[(size_t)j2 * EE];
  acc += __shfl_xor(acc, 32);
  if (lane < 32) {
    int col = hh * HDD + e;
    size_t idx = ((size_t)(b * DD + d)) * EE + col;
    h[idx] += gamma[col] * (acc / l);
  }
}

// ---------------- LayerNorm over rows of 256 ----------------
__global__ __launch_bounds__(256) void ln_k(const float* __restrict__ hin,
                                            const float* __restrict__ w,
                                            const float* __restrict__ bb,
                                            float* __restrict__ y) {
  __shared__ float red[256];
  int r = blockIdx.x, t = threadIdx.x;
  float v = hin[(size_t)r * EE + t];
  red[t] = v; __syncthreads();
  for (int off = 128; off; off >>= 1) {
    if (t < off) red[t] += red[t + off];
    __syncthreads();
  }
  float mean = red[0] / (float)EE;
  __syncthreads();
  float dv = v - mean;
  red[t] = dv * dv; __syncthreads();
  for (int off = 128; off; off >>= 1) {
    if (t < off) red[t] += red[t + off];
    __syncthreads();
  }
  float var = red[0] / (float)EE;
  y[(size_t)r * EE + t] = dv * rsqrtf(var + 1e-5f) * w[t] + bb[t];
}

// ---------------- final projection to scalar per row ----------------
__global__ __launch_bounds__(256) void out_k(const float* __restrict__ t_,
                                             const float* __restrict__ w2,
                                             const float* __restrict__ b2,
                                             float* __restrict__ out) {
  int w = threadIdx.x >> 6, lane = threadIdx.x & 63;
  int r = blockIdx.x * 4 + w;
  float s = 0.f;
  #pragma unroll
  for (int i = 0; i < 4; i++) s += t_[(size_t)r * EE + lane + i * 64] * w2[lane + i * 64];
  #pragma unroll
  for (int off = 32; off; off >>= 1) s += __shfl_xor(s, off);
  if (lane == 0) out[r] = s + b2[0];
}

extern "C" void kernel_launch(void* const* d_in, const int* in_sizes, int n_in,
                              void* d_out, int out_size, void* d_ws, size_t ws_size,
                              hipStream_t stream) {
  const float* x            = (const float*)d_in[0];
  const float* value_w      = (const float*)d_in[1];
  const float* value_b      = (const float*)d_in[2];
  const float* feature_embed= (const float*)d_in[3];
  const float* binary_w     = (const float*)d_in[4];
  const float* qw           = (const float*)d_in[5];
  const float* kw           = (const float*)d_in[6];
  const float* vw           = (const float*)d_in[7];
  const float* film_alpha   = (const float*)d_in[8];
  const float* film_a       = (const float*)d_in[9];
  const float* ln1_w        = (const float*)d_in[10];
  const float* ln1_b        = (const float*)d_in[11];
  const float* ffn_w1       = (const float*)d_in[12];
  const float* ffn_b1       = (const float*)d_in[13];
  const float* ffn_w2       = (const float*)d_in[14];
  const float* ffn_b2       = (const float*)d_in[15];
  const float* gamma_attn   = (const float*)d_in[16];
  const float* gamma_ffn    = (const float*)d_in[17];
  const float* corr_ln_w    = (const float*)d_in[18];
  const float* corr_ln_b    = (const float*)d_in[19];
  const float* corr_w1      = (const float*)d_in[20];
  const float* corr_b1      = (const float*)d_in[21];
  const float* corr_w2      = (const float*)d_in[22];
  const float* corr_b2      = (const float*)d_in[23];
  const float* alibi_strength=(const float*)d_in[24];

  float* ws = (float*)d_ws;
  float* pos    = ws;                       // D*E        = 262144
  float* qscale = pos + DD * EE;            // B*D        = 8192
  float* kv     = qscale + BD * DD;         // B*D*E      = 2097152 (reused as q)
  float* Kb     = kv + BD * DD * EE;
  float* Vb     = Kb + BD * DD * EE;
  float* hb     = Vb + BD * DD * EE;
  float* yb     = hb + BD * DD * EE;
  float* tb     = yb + BD * DD * EE;        // B*D*2E     = 4194304

  const int M = BD * DD;   // 8192

  k_qscale<<<BD, 256, 0, stream>>>(x, film_alpha, film_a, qscale);
  k_pos<<<DD, 256, 0, stream>>>(feature_embed, binary_w, pos);
  k_kvh<<<(BD * DD * EE) / 256, 256, 0, stream>>>(x, value_w, value_b, pos, kv, hb);

  gemm_k<0><<<dim3(EE / 64, M / 64), 256, 0, stream>>>(kv, kw, Kb, M, EE, EE, nullptr, nullptr);
  gemm_k<0><<<dim3(EE / 64, M / 64), 256, 0, stream>>>(kv, vw, Vb, M, EE, EE, nullptr, nullptr);

  for (int layer = 0; layer < 2; layer++) {
    gemm_k<1><<<dim3(EE / 64, M / 64), 256, 0, stream>>>(hb, qw, kv, M, EE, EE, qscale, nullptr);
    attn_k<<<(BD * HH * DD) / 4, 256, 0, stream>>>(kv, Kb, Vb, gamma_attn, alibi_strength, hb);
    ln_k<<<M, 256, 0, stream>>>(hb, ln1_w, ln1_b, yb);
    gemm_k<2><<<dim3((2 * EE) / 64, M / 64), 256, 0, stream>>>(yb, ffn_w1, tb, M, 2 * EE, EE, ffn_b1, nullptr);
    gemm_k<3><<<dim3(EE / 64, M / 64), 256, 0, stream>>>(tb, ffn_w2, hb, M, EE, 2 * EE, ffn_b2, gamma_ffn);
  }

  ln_k<<<M, 256, 0, stream>>>(hb, corr_ln_w, corr_ln_b, yb);
  gemm_k<2><<<dim3(EE / 64, M / 64), 256, 0, stream>>>(yb, corr_w1, tb, M, EE, EE, corr_b1, nullptr);
  out_k<<<M / 4, 256, 0, stream>>>(tb, corr_w2, corr_b2, (float*)d_out);
}

// Round 2
// 790.538 us; speedup vs baseline: 3.4648x; 3.4648x over previous
//
#include <hip/hip_runtime.h>
#include <math.h>

#define BD 8
#define DD 1024
#define EE 256
#define HH 8
#define HDD 32
#define NBITS 11

// ---------------- q_scale: FiLM gain from neighbor mean ----------------
__global__ __launch_bounds__(256) void k_qscale(const float* __restrict__ x,
                                                const float* __restrict__ film_alpha,
                                                const float* __restrict__ film_a,
                                                float* __restrict__ qscale) {
  __shared__ float red[256];
  int b = blockIdx.x, t = threadIdx.x;
  float s = 0.f;
  #pragma unroll
  for (int i = 0; i < 4; i++) s += x[b * DD + t + i * 256];
  red[t] = s; __syncthreads();
  for (int off = 128; off > 0; off >>= 1) {
    if (t < off) red[t] += red[t + off];
    __syncthreads();
  }
  float total = red[0];
  float ta = tanhf(film_alpha[0]);
  float fa = film_a[0];
  #pragma unroll
  for (int i = 0; i < 4; i++) {
    int d = t + i * 256;
    float xn = (total - x[b * DD + d]) / 1023.0f;
    float qs = 1.0f + ta * tanhf(fa * xn);
    qs = fminf(fmaxf(qs, 0.7f), 1.3f);
    qscale[b * DD + d] = qs;
  }
}

// ---------------- pos = feature_embed + codes @ binary_w.T ----------------
__global__ __launch_bounds__(256) void k_pos(const float* __restrict__ fe,
                                             const float* __restrict__ binary_w,
                                             float* __restrict__ pos) {
  int d = blockIdx.x, e = threadIdx.x;
  float s = fe[d * EE + e];
  int code = d + 1;
  #pragma unroll
  for (int bit = 0; bit < NBITS; bit++) {
    float cb = (float)((code >> (NBITS - 1 - bit)) & 1) - 0.5f;
    s += cb * binary_w[e * NBITS + bit];
  }
  pos[d * EE + e] = s;
}

// ---------------- kv = x*value_w + value_b + pos ; h = pos ----------------
__global__ __launch_bounds__(256) void k_kvh(const float* __restrict__ x,
                                             const float* __restrict__ value_w,
                                             const float* __restrict__ value_b,
                                             const float* __restrict__ pos,
                                             float* __restrict__ kv,
                                             float* __restrict__ h) {
  int idx = blockIdx.x * 256 + threadIdx.x;   // over B*D*E = 2M
  int e = idx & (EE - 1);
  int d = (idx >> 8) & (DD - 1);
  int b = idx >> 18;
  float p = pos[(idx & (DD * EE - 1))];
  kv[idx] = x[b * DD + d] * value_w[e] + value_b[e] + p;
  h[idx] = p;
}

// ---------------- generic tiled fp32 GEMM: C[M,N] = A[M,K] @ W[N,K]^T ----------------
// EPI 0: C = acc
// EPI 2: C = gelu_exact(acc + aux1[col])
// EPI 3: C[row,col] += aux2[col] * (acc + aux1[col])
// EPI 4: transposed write to [B,H,D,32]: C = acc
// EPI 5: transposed write to [B,H,D,32]: C = acc * aux1[row]
template <int EPI>
__global__ __launch_bounds__(256) void gemm_k(const float* __restrict__ A,
                                              const float* __restrict__ W,
                                              float* __restrict__ C,
                                              int M, int N, int K,
                                              const float* __restrict__ aux1,
                                              const float* __restrict__ aux2) {
  __shared__ float As[64][33];
  __shared__ float Ws[64][33];
  int bx = blockIdx.x, by = blockIdx.y;
  int tid = threadIdx.x;
  int tx = tid & 15, ty = tid >> 4;
  float acc[4][4] = {};
  const float* Ab = A + (size_t)(by * 64) * K;
  const float* Wb = W + (size_t)(bx * 64) * K;
  for (int k0 = 0; k0 < K; k0 += 32) {
    #pragma unroll
    for (int i = 0; i < 8; i++) {
      int l = tid + i * 256;
      int r = l >> 5, c = l & 31;
      As[r][c] = Ab[(size_t)r * K + k0 + c];
      Ws[r][c] = Wb[(size_t)r * K + k0 + c];
    }
    __syncthreads();
    #pragma unroll
    for (int kk = 0; kk < 32; kk++) {
      float a0 = As[ty * 4 + 0][kk];
      float a1 = As[ty * 4 + 1][kk];
      float a2 = As[ty * 4 + 2][kk];
      float a3 = As[ty * 4 + 3][kk];
      float b0 = Ws[tx * 4 + 0][kk];
      float b1 = Ws[tx * 4 + 1][kk];
      float b2 = Ws[tx * 4 + 2][kk];
      float b3 = Ws[tx * 4 + 3][kk];
      acc[0][0] += a0 * b0; acc[0][1] += a0 * b1; acc[0][2] += a0 * b2; acc[0][3] += a0 * b3;
      acc[1][0] += a1 * b0; acc[1][1] += a1 * b1; acc[1][2] += a1 * b2; acc[1][3] += a1 * b3;
      acc[2][0] += a2 * b0; acc[2][1] += a2 * b1; acc[2][2] += a2 * b2; acc[2][3] += a2 * b3;
      acc[3][0] += a3 * b0; acc[3][1] += a3 * b1; acc[3][2] += a3 * b2; acc[3][3] += a3 * b3;
    }
    __syncthreads();
  }
  #pragma unroll
  for (int i = 0; i < 4; i++) {
    int row = by * 64 + ty * 4 + i;
    #pragma unroll
    for (int j = 0; j < 4; j++) {
      int col = bx * 64 + tx * 4 + j;
      float v = acc[i][j];
      size_t idx = (size_t)row * N + col;
      if (EPI == 0) {
        C[idx] = v;
      } else if (EPI == 2) {
        v += aux1[col];
        C[idx] = 0.5f * v * (1.0f + erff(v * 0.70710678118654752f));
      } else if (EPI == 3) {
        v += aux1[col];
        C[idx] += aux2[col] * v;
      } else if (EPI == 4 || EPI == 5) {
        int bI = row >> 10, dI = row & 1023;
        int hI = col >> 5, eI = col & 31;
        float o = (EPI == 5) ? v * aux1[row] : v;
        C[(((size_t)(bI * HH + hI)) * DD + dI) * HDD + eI] = o;
      }
    }
  }
}

// ---------------- block-tiled flash attention ----------------
// Qt,Kt,Vt in [B,H,D,32] layout. Qt already has qscale applied.
// grid (D/128, B*H). 256 threads. h[(b*D+q)*E + hh*32 + e] += gamma * attn.
#define QB 128
#define KB 64
__global__ __launch_bounds__(256) void attn2_k(const float* __restrict__ Qt,
                                               const float* __restrict__ Kt,
                                               const float* __restrict__ Vt,
                                               const float* __restrict__ gamma,
                                               const float* __restrict__ strength_p,
                                               float* __restrict__ h) {
  __shared__ float Qts[32][QB];   // e-major
  __shared__ float Kts[32][KB];   // e-major
  __shared__ float Vs[KB][32];    // k-major
  __shared__ float Ps[KB][QB];    // k-major probabilities

  int tid = threadIdx.x;
  int tqs = tid >> 3;       // 0..31 -> 4 queries each
  int tks = tid & 7;        // 0..7  -> 8 keys (score) / 4 dims (PV)
  int bh = blockIdx.y;
  int b = bh >> 3, hh = bh & 7;
  int q0 = blockIdx.x * QB;

  const float* Qb = Qt + ((size_t)bh * DD + q0) * HDD;
  const float* Kb = Kt + (size_t)bh * DD * HDD;
  const float* Vb = Vt + (size_t)bh * DD * HDD;

  float str = fmaxf(strength_p[0], 0.0f);
  float slope = exp2f(-(float)hh / 8.0f);
  const float L2E = 1.4426950408889634f;
  const float SC = 0.17677669529663687f;  // 1/sqrt(32)

  // stage Q transposed (scaled)
  #pragma unroll
  for (int it = 0; it < 4; it++) {
    int idx = tid + it * 256;            // 0..1023
    int qq = idx >> 3;
    int e4 = (idx & 7) * 4;
    float4 v = *(const float4*)&Qb[(size_t)qq * HDD + e4];
    Qts[e4 + 0][qq] = v.x * SC;
    Qts[e4 + 1][qq] = v.y * SC;
    Qts[e4 + 2][qq] = v.z * SC;
    Qts[e4 + 3][qq] = v.w * SC;
  }

  float acc[4][4] = {};
  float m_run[4] = {-1e30f, -1e30f, -1e30f, -1e30f};
  float l_run[4] = {};

  for (int kt = 0; kt < DD / KB; kt++) {
    __syncthreads();   // protect LDS reuse from previous iteration
    // stage K (transposed) and V (row-major)
    #pragma unroll
    for (int it = 0; it < 2; it++) {
      int idx = tid + it * 256;          // 0..511
      int kk = idx >> 3;
      int e4 = (idx & 7) * 4;
      float4 kv4 = *(const float4*)&Kb[(size_t)(kt * KB + kk) * HDD + e4];
      Kts[e4 + 0][kk] = kv4.x;
      Kts[e4 + 1][kk] = kv4.y;
      Kts[e4 + 2][kk] = kv4.z;
      Kts[e4 + 3][kk] = kv4.w;
      float4 vv4 = *(const float4*)&Vb[(size_t)(kt * KB + kk) * HDD + e4];
      *(float4*)&Vs[kk][e4] = vv4;
    }
    __syncthreads();

    // scores: 4 queries x 8 keys per thread
    float s[4][8] = {};
    #pragma unroll
    for (int e = 0; e < 32; e++) {
      float4 qv = *(const float4*)&Qts[e][tqs * 4];
      float4 k0 = *(const float4*)&Kts[e][tks * 8];
      float4 k1 = *(const float4*)&Kts[e][tks * 8 + 4];
      float qa[4] = {qv.x, qv.y, qv.z, qv.w};
      float ka[8] = {k0.x, k0.y, k0.z, k0.w, k1.x, k1.y, k1.z, k1.w};
      #pragma unroll
      for (int i = 0; i < 4; i++)
        #pragma unroll
        for (int j = 0; j < 8; j++) s[i][j] += qa[i] * ka[j];
    }
    // bias + online softmax
    #pragma unroll
    for (int i = 0; i < 4; i++) {
      int qg = q0 + tqs * 4 + i;
      #pragma unroll
      for (int j = 0; j < 8; j++) {
        int kg = kt * KB + tks * 8 + j;
        float bias = (kg == qg) ? -1e30f : -str * slope * fabsf((float)(qg - kg));
        s[i][j] += bias;
      }
      float mt = fmaxf(fmaxf(fmaxf(s[i][0], s[i][1]), fmaxf(s[i][2], s[i][3])),
                       fmaxf(fmaxf(s[i][4], s[i][5]), fmaxf(s[i][6], s[i][7])));
      mt = fmaxf(mt, __shfl_xor(mt, 1));
      mt = fmaxf(mt, __shfl_xor(mt, 2));
      mt = fmaxf(mt, __shfl_xor(mt, 4));
      float mn = fmaxf(m_run[i], mt);
      float sc_ = exp2f((m_run[i] - mn) * L2E);
      m_run[i] = mn;
      float ls = 0.f;
      #pragma unroll
      for (int j = 0; j < 8; j++) {
        float p = exp2f((s[i][j] - mn) * L2E);
        s[i][j] = p;
        ls += p;
      }
      ls += __shfl_xor(ls, 1);
      ls += __shfl_xor(ls, 2);
      ls += __shfl_xor(ls, 4);
      l_run[i] = l_run[i] * sc_ + ls;
      #pragma unroll
      for (int c = 0; c < 4; c++) acc[i][c] *= sc_;
    }
    // write P (k-major)
    #pragma unroll
    for (int j = 0; j < 8; j++) {
      float4 pv = make_float4(s[0][j], s[1][j], s[2][j], s[3][j]);
      *(float4*)&Ps[tks * 8 + j][tqs * 4] = pv;
    }
    __syncthreads();

    // PV: same 4 queries, dims tks*4..+3
    #pragma unroll 4
    for (int j = 0; j < KB; j++) {
      float4 pv = *(const float4*)&Ps[j][tqs * 4];
      float4 vv = *(const float4*)&Vs[j][tks * 4];
      float pa[4] = {pv.x, pv.y, pv.z, pv.w};
      float va[4] = {vv.x, vv.y, vv.z, vv.w};
      #pragma unroll
      for (int i = 0; i < 4; i++)
        #pragma unroll
        for (int c = 0; c < 4; c++) acc[i][c] += pa[i] * va[c];
    }
  }

  // epilogue: h += gamma * acc / l
  #pragma unroll
  for (int i = 0; i < 4; i++) {
    float inv = 1.0f / l_run[i];
    int q = q0 + tqs * 4 + i;
    size_t off = ((size_t)(b * DD + q)) * EE + hh * HDD + tks * 4;
    float4 hv = *(float4*)&h[off];
    const float4 gv = *(const float4*)&gamma[hh * HDD + tks * 4];
    hv.x += gv.x * acc[i][0] * inv;
    hv.y += gv.y * acc[i][1] * inv;
    hv.z += gv.z * acc[i][2] * inv;
    hv.w += gv.w * acc[i][3] * inv;
    *(float4*)&h[off] = hv;
  }
}

// ---------------- LayerNorm over rows of 256 ----------------
__global__ __launch_bounds__(256) void ln_k(const float* __restrict__ hin,
                                            const float* __restrict__ w,
                                            const float* __restrict__ bb,
                                            float* __restrict__ y) {
  __shared__ float red[256];
  int r = blockIdx.x, t = threadIdx.x;
  float v = hin[(size_t)r * EE + t];
  red[t] = v; __syncthreads();
  for (int off = 128; off; off >>= 1) {
    if (t < off) red[t] += red[t + off];
    __syncthreads();
  }
  float mean = red[0] / (float)EE;
  __syncthreads();
  float dv = v - mean;
  red[t] = dv * dv; __syncthreads();
  for (int off = 128; off; off >>= 1) {
    if (t < off) red[t] += red[t + off];
    __syncthreads();
  }
  float var = red[0] / (float)EE;
  y[(size_t)r * EE + t] = dv * rsqrtf(var + 1e-5f) * w[t] + bb[t];
}

// ---------------- final projection to scalar per row ----------------
__global__ __launch_bounds__(256) void out_k(const float* __restrict__ t_,
                                             const float* __restrict__ w2,
                                             const float* __restrict__ b2,
                                             float* __restrict__ out) {
  int w = threadIdx.x >> 6, lane = threadIdx.x & 63;
  int r = blockIdx.x * 4 + w;
  float s = 0.f;
  #pragma unroll
  for (int i = 0; i < 4; i++) s += t_[(size_t)r * EE + lane + i * 64] * w2[lane + i * 64];
  #pragma unroll
  for (int off = 32; off; off >>= 1) s += __shfl_xor(s, off);
  if (lane == 0) out[r] = s + b2[0];
}

extern "C" void kernel_launch(void* const* d_in, const int* in_sizes, int n_in,
                              void* d_out, int out_size, void* d_ws, size_t ws_size,
                              hipStream_t stream) {
  const float* x            = (const float*)d_in[0];
  const float* value_w      = (const float*)d_in[1];
  const float* value_b      = (const float*)d_in[2];
  const float* feature_embed= (const float*)d_in[3];
  const float* binary_w     = (const float*)d_in[4];
  const float* qw           = (const float*)d_in[5];
  const float* kw           = (const float*)d_in[6];
  const float* vw           = (const float*)d_in[7];
  const float* film_alpha   = (const float*)d_in[8];
  const float* film_a       = (const float*)d_in[9];
  const float* ln1_w        = (const float*)d_in[10];
  const float* ln1_b        = (const float*)d_in[11];
  const float* ffn_w1       = (const float*)d_in[12];
  const float* ffn_b1       = (const float*)d_in[13];
  const float* ffn_w2       = (const float*)d_in[14];
  const float* ffn_b2       = (const float*)d_in[15];
  const float* gamma_attn   = (const float*)d_in[16];
  const float* gamma_ffn    = (const float*)d_in[17];
  const float* corr_ln_w    = (const float*)d_in[18];
  const float* corr_ln_b    = (const float*)d_in[19];
  const float* corr_w1      = (const float*)d_in[20];
  const float* corr_b1      = (const float*)d_in[21];
  const float* corr_w2      = (const float*)d_in[22];
  const float* corr_b2      = (const float*)d_in[23];
  const float* alibi_strength=(const float*)d_in[24];

  float* ws = (float*)d_ws;
  float* pos    = ws;                       // D*E        = 262144
  float* qscale = pos + DD * EE;            // B*D        = 8192
  float* kv     = qscale + BD * DD;         // B*D*E      (reused as Qt transposed)
  float* Kb     = kv + BD * DD * EE;        // [B,H,D,32]
  float* Vb     = Kb + BD * DD * EE;        // [B,H,D,32]
  float* hb     = Vb + BD * DD * EE;
  float* yb     = hb + BD * DD * EE;
  float* tb     = yb + BD * DD * EE;        // B*D*2E

  const int M = BD * DD;   // 8192

  k_qscale<<<BD, 256, 0, stream>>>(x, film_alpha, film_a, qscale);
  k_pos<<<DD, 256, 0, stream>>>(feature_embed, binary_w, pos);
  k_kvh<<<(BD * DD * EE) / 256, 256, 0, stream>>>(x, value_w, value_b, pos, kv, hb);

  gemm_k<4><<<dim3(EE / 64, M / 64), 256, 0, stream>>>(kv, kw, Kb, M, EE, EE, nullptr, nullptr);
  gemm_k<4><<<dim3(EE / 64, M / 64), 256, 0, stream>>>(kv, vw, Vb, M, EE, EE, nullptr, nullptr);

  for (int layer = 0; layer < 2; layer++) {
    // Q projection -> transposed layout with qscale fused (kv buffer reused as Qt)
    gemm_k<5><<<dim3(EE / 64, M / 64), 256, 0, stream>>>(hb, qw, kv, M, EE, EE, qscale, nullptr);
    attn2_k<<<dim3(DD / QB, BD * HH), 256, 0, stream>>>(kv, Kb, Vb, gamma_attn, alibi_strength, hb);
    ln_k<<<M, 256, 0, stream>>>(hb, ln1_w, ln1_b, yb);
    gemm_k<2><<<dim3((2 * EE) / 64, M / 64), 256, 0, stream>>>(yb, ffn_w1, tb, M, 2 * EE, EE, ffn_b1, nullptr);
    gemm_k<3><<<dim3(EE / 64, M / 64), 256, 0, stream>>>(tb, ffn_w2, hb, M, EE, 2 * EE, ffn_b2, gamma_ffn);
  }

  ln_k<<<M, 256, 0, stream>>>(hb, corr_ln_w, corr_ln_b, yb);
  gemm_k<2><<<dim3(EE / 64, M / 64), 256, 0, stream>>>(yb, corr_w1, tb, M, EE, EE, corr_b1, nullptr);
  out_k<<<M / 4, 256, 0, stream>>>(tb, corr_w2, corr_b2, (float*)d_out);
}

// Round 3
// 493.681 us; speedup vs baseline: 5.5483x; 1.6013x over previous
//
#include <hip/hip_runtime.h>
#include <math.h>

#define BD 8
#define DD 1024
#define EE 256
#define HH 8
#define HDD 32
#define NBITS 11

typedef __attribute__((ext_vector_type(8))) short short8;
typedef __attribute__((ext_vector_type(4))) float f4;

__device__ __forceinline__ ushort f2bf(float f) {
  unsigned u = __float_as_uint(f);
  u += 0x7fffu + ((u >> 16) & 1u);
  return (ushort)(u >> 16);
}

// ---------------- q_scale: FiLM gain from neighbor mean ----------------
__global__ __launch_bounds__(256) void k_qscale(const float* __restrict__ x,
                                                const float* __restrict__ film_alpha,
                                                const float* __restrict__ film_a,
                                                float* __restrict__ qscale) {
  __shared__ float red[256];
  int b = blockIdx.x, t = threadIdx.x;
  float s = 0.f;
  #pragma unroll
  for (int i = 0; i < 4; i++) s += x[b * DD + t + i * 256];
  red[t] = s; __syncthreads();
  for (int off = 128; off > 0; off >>= 1) {
    if (t < off) red[t] += red[t + off];
    __syncthreads();
  }
  float total = red[0];
  float ta = tanhf(film_alpha[0]);
  float fa = film_a[0];
  #pragma unroll
  for (int i = 0; i < 4; i++) {
    int d = t + i * 256;
    float xn = (total - x[b * DD + d]) / 1023.0f;
    float qs = 1.0f + ta * tanhf(fa * xn);
    qs = fminf(fmaxf(qs, 0.7f), 1.3f);
    qscale[b * DD + d] = qs;
  }
}

// ---------------- pos = feature_embed + codes @ binary_w.T ----------------
__global__ __launch_bounds__(256) void k_pos(const float* __restrict__ fe,
                                             const float* __restrict__ binary_w,
                                             float* __restrict__ pos) {
  int d = blockIdx.x, e = threadIdx.x;
  float s = fe[d * EE + e];
  int code = d + 1;
  #pragma unroll
  for (int bit = 0; bit < NBITS; bit++) {
    float cb = (float)((code >> (NBITS - 1 - bit)) & 1) - 0.5f;
    s += cb * binary_w[e * NBITS + bit];
  }
  pos[d * EE + e] = s;
}

// ---------------- kv = x*value_w + value_b + pos ; h = pos ----------------
__global__ __launch_bounds__(256) void k_kvh(const float* __restrict__ x,
                                             const float* __restrict__ value_w,
                                             const float* __restrict__ value_b,
                                             const float* __restrict__ pos,
                                             float* __restrict__ kv,
                                             float* __restrict__ h) {
  int idx = blockIdx.x * 256 + threadIdx.x;   // over B*D*E = 2M
  int e = idx & (EE - 1);
  int d = (idx >> 8) & (DD - 1);
  int b = idx >> 18;
  float p = pos[(idx & (DD * EE - 1))];
  kv[idx] = x[b * DD + d] * value_w[e] + value_b[e] + p;
  h[idx] = p;
}

// ---------------- generic tiled fp32 GEMM: C[M,N] = A[M,K] @ W[N,K]^T ----------------
// EPI 0: C = acc
// EPI 2: C = gelu_exact(acc + aux1[col])
// EPI 3: C[row,col] += aux2[col] * (acc + aux1[col])
// EPI 4: bf16 write to [B,H,D,32]: C = bf16(acc)                    (K proj)
// EPI 5: bf16 write to [B,H,D,32]: C = bf16(acc * aux1[row] * HD^-1/2) (Q proj)
// EPI 6: bf16 write to [B,H,32,D]: C = bf16(acc)                    (V proj, transposed)
template <int EPI>
__global__ __launch_bounds__(256) void gemm_k(const float* __restrict__ A,
                                              const float* __restrict__ W,
                                              float* __restrict__ C,
                                              int M, int N, int K,
                                              const float* __restrict__ aux1,
                                              const float* __restrict__ aux2) {
  __shared__ float As[64][33];
  __shared__ float Ws[64][33];
  int bx = blockIdx.x, by = blockIdx.y;
  int tid = threadIdx.x;
  int tx = tid & 15, ty = tid >> 4;
  float acc[4][4] = {};
  const float* Ab = A + (size_t)(by * 64) * K;
  const float* Wb = W + (size_t)(bx * 64) * K;
  for (int k0 = 0; k0 < K; k0 += 32) {
    #pragma unroll
    for (int i = 0; i < 8; i++) {
      int l = tid + i * 256;
      int r = l >> 5, c = l & 31;
      As[r][c] = Ab[(size_t)r * K + k0 + c];
      Ws[r][c] = Wb[(size_t)r * K + k0 + c];
    }
    __syncthreads();
    #pragma unroll
    for (int kk = 0; kk < 32; kk++) {
      float a0 = As[ty * 4 + 0][kk];
      float a1 = As[ty * 4 + 1][kk];
      float a2 = As[ty * 4 + 2][kk];
      float a3 = As[ty * 4 + 3][kk];
      float b0 = Ws[tx * 4 + 0][kk];
      float b1 = Ws[tx * 4 + 1][kk];
      float b2 = Ws[tx * 4 + 2][kk];
      float b3 = Ws[tx * 4 + 3][kk];
      acc[0][0] += a0 * b0; acc[0][1] += a0 * b1; acc[0][2] += a0 * b2; acc[0][3] += a0 * b3;
      acc[1][0] += a1 * b0; acc[1][1] += a1 * b1; acc[1][2] += a1 * b2; acc[1][3] += a1 * b3;
      acc[2][0] += a2 * b0; acc[2][1] += a2 * b1; acc[2][2] += a2 * b2; acc[2][3] += a2 * b3;
      acc[3][0] += a3 * b0; acc[3][1] += a3 * b1; acc[3][2] += a3 * b2; acc[3][3] += a3 * b3;
    }
    __syncthreads();
  }
  #pragma unroll
  for (int i = 0; i < 4; i++) {
    int row = by * 64 + ty * 4 + i;
    #pragma unroll
    for (int j = 0; j < 4; j++) {
      int col = bx * 64 + tx * 4 + j;
      float v = acc[i][j];
      size_t idx = (size_t)row * N + col;
      if (EPI == 0) {
        C[idx] = v;
      } else if (EPI == 2) {
        v += aux1[col];
        C[idx] = 0.5f * v * (1.0f + erff(v * 0.70710678118654752f));
      } else if (EPI == 3) {
        v += aux1[col];
        C[idx] += aux2[col] * v;
      } else if (EPI == 4 || EPI == 5) {
        int bI = row >> 10, dI = row & 1023;
        int hI = col >> 5, eI = col & 31;
        float o = (EPI == 5) ? v * aux1[row] * 0.17677669529663687f : v;
        ushort* Cb = (ushort*)C;
        Cb[(((size_t)(bI * HH + hI)) * DD + dI) * HDD + eI] = f2bf(o);
      } else if (EPI == 6) {
        int bI = row >> 10, dI = row & 1023;
        int hI = col >> 5, eI = col & 31;
        ushort* Cb = (ushort*)C;
        Cb[(((size_t)(bI * HH + hI)) * HDD + eI) * DD + dI] = f2bf(v);
      }
    }
  }
}

// ---------------- MFMA flash attention ----------------
// Qbf,Kbf: bf16 [B,H,D,32] (Q pre-scaled by qscale/sqrt(32)); Vtb: bf16 [B,H,32,D].
// grid (D/64, B*H), 256 threads = 4 waves, each wave owns 16 queries.
__global__ __launch_bounds__(256) void attn3_k(const ushort* __restrict__ Qbf,
                                               const ushort* __restrict__ Kbf,
                                               const ushort* __restrict__ Vtb,
                                               const float* __restrict__ gamma,
                                               const float* __restrict__ strength_p,
                                               float* __restrict__ h) {
  __shared__ __align__(16) ushort Pl[4][16][72];   // per-wave P tile, padded rows
  int tid = threadIdx.x;
  int w = tid >> 6, lane = tid & 63;
  int c = lane & 15, g = lane >> 4;
  int bh = blockIdx.y, b = bh >> 3, hh = bh & 7;
  int q0 = blockIdx.x * 64 + w * 16;
  int qg = q0 + c;
  float ss = fmaxf(strength_p[0], 0.f) * exp2f(-(float)hh / 8.0f);
  const float L2E = 1.4426950408889634f;

  // Q fragment (B operand): lane holds Q[q0+c][8g..8g+7]
  short8 qf = *(const short8*)(Qbf + (((size_t)bh * DD + qg) << 5) + (g << 3));

  f4 oacc0 = {0.f, 0.f, 0.f, 0.f};
  f4 oacc1 = {0.f, 0.f, 0.f, 0.f};
  float mrun = -1e30f, lrun = 0.f;

  const ushort* Kb0 = Kbf + (((size_t)bh * DD + c) << 5) + (g << 3);
  const ushort* Vb0 = Vtb + ((size_t)(bh * HDD + c)) * DD + (g << 3);

  for (int ks = 0; ks < DD / 64; ks++) {
    // ---- QK^T (swapped): 4 tiles of 16 keys, S^T[k][q], full K=32 contraction ----
    f4 sa[4];
    #pragma unroll
    for (int t = 0; t < 4; t++) {
      short8 kf = *(const short8*)(Kb0 + (((size_t)(ks * 64 + t * 16)) << 5));
      f4 z = {0.f, 0.f, 0.f, 0.f};
      sa[t] = __builtin_amdgcn_mfma_f32_16x16x32_bf16(kf, qf, z, 0, 0, 0);
    }
    // ---- bias + online softmax (lane owns query col c; keys 4g+r per tile) ----
    float s[16];
    float mloc = -1e30f;
    #pragma unroll
    for (int t = 0; t < 4; t++) {
      #pragma unroll
      for (int r = 0; r < 4; r++) {
        float ad = fabsf((float)(qg - (ks * 64 + t * 16 + 4 * g + r)));
        float sv = (ad == 0.f) ? -1e30f : sa[t][r] - ss * ad;
        s[t * 4 + r] = sv;
        mloc = fmaxf(mloc, sv);
      }
    }
    mloc = fmaxf(mloc, __shfl_xor(mloc, 16));
    mloc = fmaxf(mloc, __shfl_xor(mloc, 32));
    float mnew = fmaxf(mrun, mloc);
    float sc_ = exp2f((mrun - mnew) * L2E);
    mrun = mnew;
    float ll = 0.f;
    #pragma unroll
    for (int i = 0; i < 16; i++) {
      float p = exp2f((s[i] - mnew) * L2E);
      s[i] = p;
      ll += p;
    }
    ll += __shfl_xor(ll, 16);
    ll += __shfl_xor(ll, 32);
    lrun = lrun * sc_ + ll;
    // rescale O accumulators (rows are q = 4g+r; fetch that query's scale)
    #pragma unroll
    for (int r = 0; r < 4; r++) {
      float sq = __shfl(sc_, 4 * g + r);
      oacc0[r] *= sq;
      oacc1[r] *= sq;
    }
    // ---- pack P (bf16) into per-wave LDS: row=q(c), col=key-in-step ----
    #pragma unroll
    for (int t = 0; t < 4; t++) {
      uint2 u;
      u.x = (uint)f2bf(s[t * 4 + 0]) | ((uint)f2bf(s[t * 4 + 1]) << 16);
      u.y = (uint)f2bf(s[t * 4 + 2]) | ((uint)f2bf(s[t * 4 + 3]) << 16);
      *(uint2*)&Pl[w][c][t * 16 + 4 * g] = u;
    }
    // ---- PV: O[q][e] += P[q][k] V[k][e], two K=32 halves, two e-tiles ----
    #pragma unroll
    for (int hb2 = 0; hb2 < 2; hb2++) {
      short8 pa = *(const short8*)&Pl[w][c][hb2 * 32 + 8 * g];
      short8 v0 = *(const short8*)(Vb0 + ks * 64 + hb2 * 32);
      short8 v1 = *(const short8*)(Vb0 + (size_t)16 * DD + ks * 64 + hb2 * 32);
      oacc0 = __builtin_amdgcn_mfma_f32_16x16x32_bf16(pa, v0, oacc0, 0, 0, 0);
      oacc1 = __builtin_amdgcn_mfma_f32_16x16x32_bf16(pa, v1, oacc1, 0, 0, 0);
    }
  }

  // ---- epilogue: h += gamma * O / l ----
  float linv = 1.0f / lrun;
  #pragma unroll
  for (int r = 0; r < 4; r++) {
    float li = __shfl(linv, 4 * g + r);
    int q = q0 + 4 * g + r;
    size_t base = ((size_t)(b * DD + q)) * EE + hh * HDD;
    int e0 = c, e1 = 16 + c;
    h[base + e0] += gamma[hh * HDD + e0] * oacc0[r] * li;
    h[base + e1] += gamma[hh * HDD + e1] * oacc1[r] * li;
  }
}

// ---------------- LayerNorm over rows of 256 ----------------
__global__ __launch_bounds__(256) void ln_k(const float* __restrict__ hin,
                                            const float* __restrict__ w,
                                            const float* __restrict__ bb,
                                            float* __restrict__ y) {
  __shared__ float red[256];
  int r = blockIdx.x, t = threadIdx.x;
  float v = hin[(size_t)r * EE + t];
  red[t] = v; __syncthreads();
  for (int off = 128; off; off >>= 1) {
    if (t < off) red[t] += red[t + off];
    __syncthreads();
  }
  float mean = red[0] / (float)EE;
  __syncthreads();
  float dv = v - mean;
  red[t] = dv * dv; __syncthreads();
  for (int off = 128; off; off >>= 1) {
    if (t < off) red[t] += red[t + off];
    __syncthreads();
  }
  float var = red[0] / (float)EE;
  y[(size_t)r * EE + t] = dv * rsqrtf(var + 1e-5f) * w[t] + bb[t];
}

// ---------------- final projection to scalar per row ----------------
__global__ __launch_bounds__(256) void out_k(const float* __restrict__ t_,
                                             const float* __restrict__ w2,
                                             const float* __restrict__ b2,
                                             float* __restrict__ out) {
  int w = threadIdx.x >> 6, lane = threadIdx.x & 63;
  int r = blockIdx.x * 4 + w;
  float s = 0.f;
  #pragma unroll
  for (int i = 0; i < 4; i++) s += t_[(size_t)r * EE + lane + i * 64] * w2[lane + i * 64];
  #pragma unroll
  for (int off = 32; off; off >>= 1) s += __shfl_xor(s, off);
  if (lane == 0) out[r] = s + b2[0];
}

extern "C" void kernel_launch(void* const* d_in, const int* in_sizes, int n_in,
                              void* d_out, int out_size, void* d_ws, size_t ws_size,
                              hipStream_t stream) {
  const float* x            = (const float*)d_in[0];
  const float* value_w      = (const float*)d_in[1];
  const float* value_b      = (const float*)d_in[2];
  const float* feature_embed= (const float*)d_in[3];
  const float* binary_w     = (const float*)d_in[4];
  const float* qw           = (const float*)d_in[5];
  const float* kw           = (const float*)d_in[6];
  const float* vw           = (const float*)d_in[7];
  const float* film_alpha   = (const float*)d_in[8];
  const float* film_a       = (const float*)d_in[9];
  const float* ln1_w        = (const float*)d_in[10];
  const float* ln1_b        = (const float*)d_in[11];
  const float* ffn_w1       = (const float*)d_in[12];
  const float* ffn_b1       = (const float*)d_in[13];
  const float* ffn_w2       = (const float*)d_in[14];
  const float* ffn_b2       = (const float*)d_in[15];
  const float* gamma_attn   = (const float*)d_in[16];
  const float* gamma_ffn    = (const float*)d_in[17];
  const float* corr_ln_w    = (const float*)d_in[18];
  const float* corr_ln_b    = (const float*)d_in[19];
  const float* corr_w1      = (const float*)d_in[20];
  const float* corr_b1      = (const float*)d_in[21];
  const float* corr_w2      = (const float*)d_in[22];
  const float* corr_b2      = (const float*)d_in[23];
  const float* alibi_strength=(const float*)d_in[24];

  float* ws = (float*)d_ws;
  float* pos    = ws;                          // 262144 f
  float* qscale = pos + DD * EE;               // 8192 f
  float* kv     = qscale + BD * DD;            // 2M f
  float* hb     = kv + (size_t)BD * DD * EE;   // 2M f
  float* yb     = hb + (size_t)BD * DD * EE;   // 2M f
  float* tb     = yb + (size_t)BD * DD * EE;   // 4M f
  ushort* Qbf   = (ushort*)(tb + (size_t)BD * DD * 2 * EE);  // 2M us
  ushort* Kbf   = Qbf + (size_t)BD * DD * HDD * HH;          // 2M us
  ushort* Vtb   = Kbf + (size_t)BD * DD * HDD * HH;          // 2M us

  const int M = BD * DD;   // 8192

  k_qscale<<<BD, 256, 0, stream>>>(x, film_alpha, film_a, qscale);
  k_pos<<<DD, 256, 0, stream>>>(feature_embed, binary_w, pos);
  k_kvh<<<(BD * DD * EE) / 256, 256, 0, stream>>>(x, value_w, value_b, pos, kv, hb);

  gemm_k<4><<<dim3(EE / 64, M / 64), 256, 0, stream>>>(kv, kw, (float*)Kbf, M, EE, EE, nullptr, nullptr);
  gemm_k<6><<<dim3(EE / 64, M / 64), 256, 0, stream>>>(kv, vw, (float*)Vtb, M, EE, EE, nullptr, nullptr);

  for (int layer = 0; layer < 2; layer++) {
    gemm_k<5><<<dim3(EE / 64, M / 64), 256, 0, stream>>>(hb, qw, (float*)Qbf, M, EE, EE, qscale, nullptr);
    attn3_k<<<dim3(DD / 64, BD * HH), 256, 0, stream>>>(Qbf, Kbf, Vtb, gamma_attn, alibi_strength, hb);
    ln_k<<<M, 256, 0, stream>>>(hb, ln1_w, ln1_b, yb);
    gemm_k<2><<<dim3((2 * EE) / 64, M / 64), 256, 0, stream>>>(yb, ffn_w1, tb, M, 2 * EE, EE, ffn_b1, nullptr);
    gemm_k<3><<<dim3(EE / 64, M / 64), 256, 0, stream>>>(tb, ffn_w2, hb, M, EE, 2 * EE, ffn_b2, gamma_ffn);
  }

  ln_k<<<M, 256, 0, stream>>>(hb, corr_ln_w, corr_ln_b, yb);
  gemm_k<2><<<dim3(EE / 64, M / 64), 256, 0, stream>>>(yb, corr_w1, tb, M, EE, EE, corr_b1, nullptr);
  out_k<<<M / 4, 256, 0, stream>>>(tb, corr_w2, corr_b2, (float*)d_out);
}

// Round 4
// 223.745 us; speedup vs baseline: 12.2420x; 2.2065x over previous
//
#include <hip/hip_runtime.h>
#include <math.h>

#define BD 8
#define DD 1024
#define EE 256
#define HH 8
#define HDD 32
#define NBITS 11

typedef __attribute__((ext_vector_type(8))) short short8;
typedef __attribute__((ext_vector_type(4))) float f4;

__device__ __forceinline__ ushort f2bf(float f) {
  unsigned u = __float_as_uint(f);
  u += 0x7fffu + ((u >> 16) & 1u);
  return (ushort)(u >> 16);
}
__device__ __forceinline__ float bf2f(ushort u) {
  return __uint_as_float(((unsigned)u) << 16);
}
__device__ __forceinline__ void async_copy16(ushort* lds, const ushort* g) {
  __builtin_amdgcn_global_load_lds((const __attribute__((address_space(1))) void*)g,
                                   (__attribute__((address_space(3))) void*)lds, 16, 0, 0);
}

// ---------------- q_scale: FiLM gain from neighbor mean ----------------
__global__ __launch_bounds__(256) void k_qscale(const float* __restrict__ x,
                                                const float* __restrict__ film_alpha,
                                                const float* __restrict__ film_a,
                                                float* __restrict__ qscale) {
  __shared__ float red[256];
  int b = blockIdx.x, t = threadIdx.x;
  float s = 0.f;
  #pragma unroll
  for (int i = 0; i < 4; i++) s += x[b * DD + t + i * 256];
  red[t] = s; __syncthreads();
  for (int off = 128; off > 0; off >>= 1) {
    if (t < off) red[t] += red[t + off];
    __syncthreads();
  }
  float total = red[0];
  float ta = tanhf(film_alpha[0]);
  float fa = film_a[0];
  #pragma unroll
  for (int i = 0; i < 4; i++) {
    int d = t + i * 256;
    float xn = (total - x[b * DD + d]) / 1023.0f;
    float qs = 1.0f + ta * tanhf(fa * xn);
    qs = fminf(fmaxf(qs, 0.7f), 1.3f);
    qscale[b * DD + d] = qs;
  }
}

// ---------------- pos = feature_embed + codes @ binary_w.T ----------------
__global__ __launch_bounds__(256) void k_pos(const float* __restrict__ fe,
                                             const float* __restrict__ binary_w,
                                             float* __restrict__ pos) {
  int d = blockIdx.x, e = threadIdx.x;
  float s = fe[d * EE + e];
  int code = d + 1;
  #pragma unroll
  for (int bit = 0; bit < NBITS; bit++) {
    float cb = (float)((code >> (NBITS - 1 - bit)) & 1) - 0.5f;
    s += cb * binary_w[e * NBITS + bit];
  }
  pos[d * EE + e] = s;
}

// ---------------- kv/h init: kv_bf = bf16(x*vw+vb+pos); h=pos; h_bf=bf16(pos) ----------------
__global__ __launch_bounds__(256) void k_kvh(const float* __restrict__ x,
                                             const float* __restrict__ value_w,
                                             const float* __restrict__ value_b,
                                             const float* __restrict__ pos,
                                             ushort* __restrict__ kv_bf,
                                             float* __restrict__ h,
                                             ushort* __restrict__ h_bf) {
  int idx = blockIdx.x * 256 + threadIdx.x;   // over B*D*E = 2M
  int e = idx & (EE - 1);
  int d = (idx >> 8) & (DD - 1);
  int b = idx >> 18;
  float p = pos[(idx & (DD * EE - 1))];
  kv_bf[idx] = f2bf(x[b * DD + d] * value_w[e] + value_b[e] + p);
  h[idx] = p;
  h_bf[idx] = f2bf(p);
}

// ---------------- weights -> bf16 (one launch) ----------------
// layout: qw[65536] kw[65536] vw[65536] w1[131072] w2[131072] cw1[65536]
__global__ __launch_bounds__(256) void k_wconv(const float* __restrict__ qw,
                                               const float* __restrict__ kw,
                                               const float* __restrict__ vw,
                                               const float* __restrict__ w1,
                                               const float* __restrict__ w2,
                                               const float* __restrict__ cw1,
                                               ushort* __restrict__ o) {
  int i = blockIdx.x * 256 + threadIdx.x;
  float v;
  if (i < 65536) v = qw[i];
  else if (i < 131072) v = kw[i - 65536];
  else if (i < 196608) v = vw[i - 131072];
  else if (i < 327680) v = w1[i - 196608];
  else if (i < 458752) v = w2[i - 327680];
  else v = cw1[i - 458752];
  o[i] = f2bf(v);
}

// ---------------- MFMA GEMM: C[M,N] = A[M,K] @ W[N,K]^T, bf16 in / fp32 acc ----------------
// 64x64 tile, BK=64, 4 waves (2x2), wave tile 32x32.
// EPI 0: K proj  -> bf16 [B,H,D,32]
// EPI 1: Q proj  -> bf16 [B,H,D,32], scaled by aux1[row]/sqrt(32)
// EPI 2: V proj  -> bf16 [B,H,32,D]
// EPI 3: GELU    -> bf16 [M,N], v = gelu(acc + aux1[col])
// EPI 4: RES     -> hb[row,col] += aux2[col]*(acc+aux1[col]) (fp32), C = bf16(new hb)
template <int EPI, int KT>
__global__ __launch_bounds__(256) void mgemm_k(const ushort* __restrict__ A,
                                               const ushort* __restrict__ Bw,
                                               ushort* __restrict__ C,
                                               int N,
                                               const float* __restrict__ aux1,
                                               const float* __restrict__ aux2,
                                               float* __restrict__ hb) {
  __shared__ ushort As[64 * 64];
  __shared__ ushort Bs[64 * 64];
  int tid = threadIdx.x;
  int w = tid >> 6, lane = tid & 63;
  int c = lane & 15, g = lane >> 4;
  int wr = w >> 1, wc = w & 1;
  int lr = lane >> 3, lsl = lane & 7;

  const ushort* Ab = A + (size_t)(blockIdx.y * 64) * KT;
  const ushort* Bb = Bw + (size_t)(blockIdx.x * 64) * KT;

  f4 acc[2][2] = {};

  for (int kt = 0; kt < KT / 64; kt++) {
    if (kt) __syncthreads();
    // stage A,B tiles: linear LDS dest, source slot pre-XOR-swizzled
    #pragma unroll
    for (int j = 0; j < 2; j++) {
      int rl = j * 32 + w * 8 + lr;
      int slot = lsl ^ (rl & 7);
      async_copy16(&As[(j * 32 + w * 8) * 64], Ab + (size_t)rl * KT + kt * 64 + slot * 8);
      async_copy16(&Bs[(j * 32 + w * 8) * 64], Bb + (size_t)rl * KT + kt * 64 + slot * 8);
    }
    __syncthreads();   // drains vmcnt(0) + barrier
    #pragma unroll
    for (int ks2 = 0; ks2 < 2; ks2++) {
      short8 af[2], bf_[2];
      #pragma unroll
      for (int mi = 0; mi < 2; mi++) {
        int rowl = wr * 32 + mi * 16 + c;
        int slot = (ks2 * 4 + g) ^ (rowl & 7);
        af[mi] = *(const short8*)&As[rowl * 64 + slot * 8];
      }
      #pragma unroll
      for (int ni = 0; ni < 2; ni++) {
        int rowl = wc * 32 + ni * 16 + c;
        int slot = (ks2 * 4 + g) ^ (rowl & 7);
        bf_[ni] = *(const short8*)&Bs[rowl * 64 + slot * 8];
      }
      #pragma unroll
      for (int mi = 0; mi < 2; mi++)
        #pragma unroll
        for (int ni = 0; ni < 2; ni++)
          acc[mi][ni] = __builtin_amdgcn_mfma_f32_16x16x32_bf16(af[mi], bf_[ni], acc[mi][ni], 0, 0, 0);
    }
  }

  // epilogue: D element (mi,ni,r) -> row = m0+mi*16+4g+r, col = n0+ni*16+c
  int m0 = blockIdx.y * 64 + wr * 32;
  int n0 = blockIdx.x * 64 + wc * 32;
  #pragma unroll
  for (int mi = 0; mi < 2; mi++) {
    #pragma unroll
    for (int ni = 0; ni < 2; ni++) {
      #pragma unroll
      for (int r = 0; r < 4; r++) {
        int row = m0 + mi * 16 + 4 * g + r;
        int col = n0 + ni * 16 + c;
        float v = acc[mi][ni][r];
        if (EPI == 0 || EPI == 1) {
          int bI = row >> 10, dI = row & 1023;
          int hI = col >> 5, eI = col & 31;
          float o = (EPI == 1) ? v * aux1[row] * 0.17677669529663687f : v;
          C[(((size_t)(bI * HH + hI)) * DD + dI) * HDD + eI] = f2bf(o);
        } else if (EPI == 2) {
          int bI = row >> 10, dI = row & 1023;
          int hI = col >> 5, eI = col & 31;
          C[(((size_t)(bI * HH + hI)) * HDD + eI) * DD + dI] = f2bf(v);
        } else if (EPI == 3) {
          v += aux1[col];
          float gl = 0.5f * v * (1.0f + erff(v * 0.70710678118654752f));
          C[(size_t)row * N + col] = f2bf(gl);
        } else if (EPI == 4) {
          v += aux1[col];
          size_t idx = (size_t)row * EE + col;
          float nh = hb[idx] + aux2[col] * v;
          hb[idx] = nh;
          C[idx] = f2bf(nh);
        }
      }
    }
  }
}

// ---------------- MFMA flash attention ----------------
// Qbf,Kbf: bf16 [B,H,D,32] (Q pre-scaled by qscale/sqrt(32)); Vtb: bf16 [B,H,32,D].
// grid (D/64, B*H), 256 threads = 4 waves, each wave owns 16 queries.
__global__ __launch_bounds__(256) void attn3_k(const ushort* __restrict__ Qbf,
                                               const ushort* __restrict__ Kbf,
                                               const ushort* __restrict__ Vtb,
                                               const float* __restrict__ gamma,
                                               const float* __restrict__ strength_p,
                                               float* __restrict__ h) {
  __shared__ __align__(16) ushort Pl[4][16][72];   // per-wave P tile, padded rows
  int tid = threadIdx.x;
  int w = tid >> 6, lane = tid & 63;
  int c = lane & 15, g = lane >> 4;
  int bh = blockIdx.y, b = bh >> 3, hh = bh & 7;
  int q0 = blockIdx.x * 64 + w * 16;
  int qg = q0 + c;
  float ss = fmaxf(strength_p[0], 0.f) * exp2f(-(float)hh / 8.0f);
  const float L2E = 1.4426950408889634f;

  // Q fragment (B operand): lane holds Q[q0+c][8g..8g+7]
  short8 qf = *(const short8*)(Qbf + (((size_t)bh * DD + qg) << 5) + (g << 3));

  f4 oacc0 = {0.f, 0.f, 0.f, 0.f};
  f4 oacc1 = {0.f, 0.f, 0.f, 0.f};
  float mrun = -1e30f, lrun = 0.f;

  const ushort* Kb0 = Kbf + (((size_t)bh * DD + c) << 5) + (g << 3);
  const ushort* Vb0 = Vtb + ((size_t)(bh * HDD + c)) * DD + (g << 3);

  for (int ks = 0; ks < DD / 64; ks++) {
    // ---- QK^T (swapped): 4 tiles of 16 keys, S^T[k][q], full K=32 contraction ----
    f4 sa[4];
    #pragma unroll
    for (int t = 0; t < 4; t++) {
      short8 kf = *(const short8*)(Kb0 + (((size_t)(ks * 64 + t * 16)) << 5));
      f4 z = {0.f, 0.f, 0.f, 0.f};
      sa[t] = __builtin_amdgcn_mfma_f32_16x16x32_bf16(kf, qf, z, 0, 0, 0);
    }
    // ---- bias + online softmax (lane owns query col c; keys 4g+r per tile) ----
    float s[16];
    float mloc = -1e30f;
    #pragma unroll
    for (int t = 0; t < 4; t++) {
      #pragma unroll
      for (int r = 0; r < 4; r++) {
        float ad = fabsf((float)(qg - (ks * 64 + t * 16 + 4 * g + r)));
        float sv = (ad == 0.f) ? -1e30f : sa[t][r] - ss * ad;
        s[t * 4 + r] = sv;
        mloc = fmaxf(mloc, sv);
      }
    }
    mloc = fmaxf(mloc, __shfl_xor(mloc, 16));
    mloc = fmaxf(mloc, __shfl_xor(mloc, 32));
    float mnew = fmaxf(mrun, mloc);
    float sc_ = exp2f((mrun - mnew) * L2E);
    mrun = mnew;
    float ll = 0.f;
    #pragma unroll
    for (int i = 0; i < 16; i++) {
      float p = exp2f((s[i] - mnew) * L2E);
      s[i] = p;
      ll += p;
    }
    ll += __shfl_xor(ll, 16);
    ll += __shfl_xor(ll, 32);
    lrun = lrun * sc_ + ll;
    // rescale O accumulators (rows are q = 4g+r; fetch that query's scale)
    #pragma unroll
    for (int r = 0; r < 4; r++) {
      float sq = __shfl(sc_, 4 * g + r);
      oacc0[r] *= sq;
      oacc1[r] *= sq;
    }
    // ---- pack P (bf16) into per-wave LDS: row=q(c), col=key-in-step ----
    #pragma unroll
    for (int t = 0; t < 4; t++) {
      uint2 u;
      u.x = (uint)f2bf(s[t * 4 + 0]) | ((uint)f2bf(s[t * 4 + 1]) << 16);
      u.y = (uint)f2bf(s[t * 4 + 2]) | ((uint)f2bf(s[t * 4 + 3]) << 16);
      *(uint2*)&Pl[w][c][t * 16 + 4 * g] = u;
    }
    // ---- PV: O[q][e] += P[q][k] V[k][e], two K=32 halves, two e-tiles ----
    #pragma unroll
    for (int hb2 = 0; hb2 < 2; hb2++) {
      short8 pa = *(const short8*)&Pl[w][c][hb2 * 32 + 8 * g];
      short8 v0 = *(const short8*)(Vb0 + ks * 64 + hb2 * 32);
      short8 v1 = *(const short8*)(Vb0 + (size_t)16 * DD + ks * 64 + hb2 * 32);
      oacc0 = __builtin_amdgcn_mfma_f32_16x16x32_bf16(pa, v0, oacc0, 0, 0, 0);
      oacc1 = __builtin_amdgcn_mfma_f32_16x16x32_bf16(pa, v1, oacc1, 0, 0, 0);
    }
  }

  // ---- epilogue: h += gamma * O / l ----
  float linv = 1.0f / lrun;
  #pragma unroll
  for (int r = 0; r < 4; r++) {
    float li = __shfl(linv, 4 * g + r);
    int q = q0 + 4 * g + r;
    size_t base = ((size_t)(b * DD + q)) * EE + hh * HDD;
    int e0 = c, e1 = 16 + c;
    h[base + e0] += gamma[hh * HDD + e0] * oacc0[r] * li;
    h[base + e1] += gamma[hh * HDD + e1] * oacc1[r] * li;
  }
}

// ---------------- LayerNorm over rows of 256 -> bf16 ----------------
__global__ __launch_bounds__(256) void ln_k(const float* __restrict__ hin,
                                            const float* __restrict__ w,
                                            const float* __restrict__ bb,
                                            ushort* __restrict__ y) {
  __shared__ float red[256];
  int r = blockIdx.x, t = threadIdx.x;
  float v = hin[(size_t)r * EE + t];
  red[t] = v; __syncthreads();
  for (int off = 128; off; off >>= 1) {
    if (t < off) red[t] += red[t + off];
    __syncthreads();
  }
  float mean = red[0] / (float)EE;
  __syncthreads();
  float dv = v - mean;
  red[t] = dv * dv; __syncthreads();
  for (int off = 128; off; off >>= 1) {
    if (t < off) red[t] += red[t + off];
    __syncthreads();
  }
  float var = red[0] / (float)EE;
  y[(size_t)r * EE + t] = f2bf(dv * rsqrtf(var + 1e-5f) * w[t] + bb[t]);
}

// ---------------- final projection to scalar per row ----------------
__global__ __launch_bounds__(256) void out_k(const ushort* __restrict__ t_,
                                             const float* __restrict__ w2,
                                             const float* __restrict__ b2,
                                             float* __restrict__ out) {
  int w = threadIdx.x >> 6, lane = threadIdx.x & 63;
  int r = blockIdx.x * 4 + w;
  float s = 0.f;
  #pragma unroll
  for (int i = 0; i < 4; i++) s += bf2f(t_[(size_t)r * EE + lane + i * 64]) * w2[lane + i * 64];
  #pragma unroll
  for (int off = 32; off; off >>= 1) s += __shfl_xor(s, off);
  if (lane == 0) out[r] = s + b2[0];
}

extern "C" void kernel_launch(void* const* d_in, const int* in_sizes, int n_in,
                              void* d_out, int out_size, void* d_ws, size_t ws_size,
                              hipStream_t stream) {
  const float* x            = (const float*)d_in[0];
  const float* value_w      = (const float*)d_in[1];
  const float* value_b      = (const float*)d_in[2];
  const float* feature_embed= (const float*)d_in[3];
  const float* binary_w     = (const float*)d_in[4];
  const float* qw           = (const float*)d_in[5];
  const float* kw           = (const float*)d_in[6];
  const float* vw           = (const float*)d_in[7];
  const float* film_alpha   = (const float*)d_in[8];
  const float* film_a       = (const float*)d_in[9];
  const float* ln1_w        = (const float*)d_in[10];
  const float* ln1_b        = (const float*)d_in[11];
  const float* ffn_w1       = (const float*)d_in[12];
  const float* ffn_b1       = (const float*)d_in[13];
  const float* ffn_w2       = (const float*)d_in[14];
  const float* ffn_b2       = (const float*)d_in[15];
  const float* gamma_attn   = (const float*)d_in[16];
  const float* gamma_ffn    = (const float*)d_in[17];
  const float* corr_ln_w    = (const float*)d_in[18];
  const float* corr_ln_b    = (const float*)d_in[19];
  const float* corr_w1      = (const float*)d_in[20];
  const float* corr_b1      = (const float*)d_in[21];
  const float* corr_w2      = (const float*)d_in[22];
  const float* corr_b2      = (const float*)d_in[23];
  const float* alibi_strength=(const float*)d_in[24];

  const size_t ME = (size_t)BD * DD * EE;   // 2M
  float* ws = (float*)d_ws;
  float* pos    = ws;                       // 262144 f
  float* qscale = pos + DD * EE;            // 8192 f
  float* hb     = qscale + BD * DD;         // 2M f
  ushort* kv_bf = (ushort*)(hb + ME);       // 2M us
  ushort* hb_bf = kv_bf + ME;               // 2M us
  ushort* yb_bf = hb_bf + ME;               // 2M us
  ushort* tb_bf = yb_bf + ME;               // 4M us
  ushort* Qbf   = tb_bf + 2 * ME;           // 2M us
  ushort* Kbf   = Qbf + ME;                 // 2M us
  ushort* Vtb   = Kbf + ME;                 // 2M us
  ushort* wbf   = Vtb + ME;                 // 524288 us
  ushort* qwb   = wbf;
  ushort* kwb   = wbf + 65536;
  ushort* vwb   = wbf + 131072;
  ushort* w1b   = wbf + 196608;
  ushort* w2b   = wbf + 327680;
  ushort* cw1b  = wbf + 458752;

  const int M = BD * DD;   // 8192

  k_qscale<<<BD, 256, 0, stream>>>(x, film_alpha, film_a, qscale);
  k_pos<<<DD, 256, 0, stream>>>(feature_embed, binary_w, pos);
  k_kvh<<<(BD * DD * EE) / 256, 256, 0, stream>>>(x, value_w, value_b, pos, kv_bf, hb, hb_bf);
  k_wconv<<<524288 / 256, 256, 0, stream>>>(qw, kw, vw, ffn_w1, ffn_w2, corr_w1, wbf);

  mgemm_k<0, 256><<<dim3(EE / 64, M / 64), 256, 0, stream>>>(kv_bf, kwb, Kbf, EE, nullptr, nullptr, nullptr);
  mgemm_k<2, 256><<<dim3(EE / 64, M / 64), 256, 0, stream>>>(kv_bf, vwb, Vtb, EE, nullptr, nullptr, nullptr);

  for (int layer = 0; layer < 2; layer++) {
    mgemm_k<1, 256><<<dim3(EE / 64, M / 64), 256, 0, stream>>>(hb_bf, qwb, Qbf, EE, qscale, nullptr, nullptr);
    attn3_k<<<dim3(DD / 64, BD * HH), 256, 0, stream>>>(Qbf, Kbf, Vtb, gamma_attn, alibi_strength, hb);
    ln_k<<<M, 256, 0, stream>>>(hb, ln1_w, ln1_b, yb_bf);
    mgemm_k<3, 256><<<dim3((2 * EE) / 64, M / 64), 256, 0, stream>>>(yb_bf, w1b, tb_bf, 2 * EE, ffn_b1, nullptr, nullptr);
    mgemm_k<4, 512><<<dim3(EE / 64, M / 64), 256, 0, stream>>>(tb_bf, w2b, hb_bf, EE, ffn_b2, gamma_ffn, hb);
  }

  ln_k<<<M, 256, 0, stream>>>(hb, corr_ln_w, corr_ln_b, yb_bf);
  mgemm_k<3, 256><<<dim3(EE / 64, M / 64), 256, 0, stream>>>(yb_bf, cw1b, tb_bf, EE, corr_b1, nullptr, nullptr);
  out_k<<<M / 4, 256, 0, stream>>>(tb_bf, corr_w2, corr_b2, (float*)d_out);
}

// Round 5
// 197.739 us; speedup vs baseline: 13.8520x; 1.1315x over previous
//
#include <hip/hip_runtime.h>
#include <math.h>

#define BD 8
#define DD 1024
#define EE 256
#define HH 8
#define HDD 32
#define NBITS 11

typedef __attribute__((ext_vector_type(8))) short short8;
typedef __attribute__((ext_vector_type(4))) float f4;

__device__ __forceinline__ ushort f2bf(float f) {
  unsigned u = __float_as_uint(f);
  u += 0x7fffu + ((u >> 16) & 1u);
  return (ushort)(u >> 16);
}
__device__ __forceinline__ float bf2f(ushort u) {
  return __uint_as_float(((unsigned)u) << 16);
}
__device__ __forceinline__ void async_copy16(ushort* lds, const ushort* g) {
  __builtin_amdgcn_global_load_lds((const __attribute__((address_space(1))) void*)g,
                                   (__attribute__((address_space(3))) void*)lds, 16, 0, 0);
}

// ---------------- q_scale: FiLM gain from neighbor mean ----------------
__global__ __launch_bounds__(256) void k_qscale(const float* __restrict__ x,
                                                const float* __restrict__ film_alpha,
                                                const float* __restrict__ film_a,
                                                float* __restrict__ qscale) {
  __shared__ float red[256];
  int b = blockIdx.x, t = threadIdx.x;
  float s = 0.f;
  #pragma unroll
  for (int i = 0; i < 4; i++) s += x[b * DD + t + i * 256];
  red[t] = s; __syncthreads();
  for (int off = 128; off > 0; off >>= 1) {
    if (t < off) red[t] += red[t + off];
    __syncthreads();
  }
  float total = red[0];
  float ta = tanhf(film_alpha[0]);
  float fa = film_a[0];
  #pragma unroll
  for (int i = 0; i < 4; i++) {
    int d = t + i * 256;
    float xn = (total - x[b * DD + d]) / 1023.0f;
    float qs = 1.0f + ta * tanhf(fa * xn);
    qs = fminf(fmaxf(qs, 0.7f), 1.3f);
    qscale[b * DD + d] = qs;
  }
}

// ---------------- pos = feature_embed + codes @ binary_w.T ----------------
__global__ __launch_bounds__(256) void k_pos(const float* __restrict__ fe,
                                             const float* __restrict__ binary_w,
                                             float* __restrict__ pos) {
  int d = blockIdx.x, e = threadIdx.x;
  float s = fe[d * EE + e];
  int code = d + 1;
  #pragma unroll
  for (int bit = 0; bit < NBITS; bit++) {
    float cb = (float)((code >> (NBITS - 1 - bit)) & 1) - 0.5f;
    s += cb * binary_w[e * NBITS + bit];
  }
  pos[d * EE + e] = s;
}

// ---------------- kv/h init: kv_bf = bf16(x*vw+vb+pos); h=pos; h_bf=bf16(pos) ----------------
__global__ __launch_bounds__(256) void k_kvh(const float* __restrict__ x,
                                             const float* __restrict__ value_w,
                                             const float* __restrict__ value_b,
                                             const float* __restrict__ pos,
                                             ushort* __restrict__ kv_bf,
                                             float* __restrict__ h,
                                             ushort* __restrict__ h_bf) {
  int idx = blockIdx.x * 256 + threadIdx.x;   // over B*D*E = 2M
  int e = idx & (EE - 1);
  int d = (idx >> 8) & (DD - 1);
  int b = idx >> 18;
  float p = pos[(idx & (DD * EE - 1))];
  kv_bf[idx] = f2bf(x[b * DD + d] * value_w[e] + value_b[e] + p);
  h[idx] = p;
  h_bf[idx] = f2bf(p);
}

// ---------------- weights -> bf16 (one launch) ----------------
// layout: qw[65536] kw[65536] vw[65536] w1[131072] w2[131072] cw1[65536]
__global__ __launch_bounds__(256) void k_wconv(const float* __restrict__ qw,
                                               const float* __restrict__ kw,
                                               const float* __restrict__ vw,
                                               const float* __restrict__ w1,
                                               const float* __restrict__ w2,
                                               const float* __restrict__ cw1,
                                               ushort* __restrict__ o) {
  int i = blockIdx.x * 256 + threadIdx.x;
  float v;
  if (i < 65536) v = qw[i];
  else if (i < 131072) v = kw[i - 65536];
  else if (i < 196608) v = vw[i - 131072];
  else if (i < 327680) v = w1[i - 196608];
  else if (i < 458752) v = w2[i - 327680];
  else v = cw1[i - 458752];
  o[i] = f2bf(v);
}

// ---------------- MFMA GEMM: C[M,N] = A[M,K] @ W[N,K]^T, bf16 in / fp32 acc ----------------
// 64x64 tile, BK=64, 4 waves (2x2), wave tile 32x32.
// EPI 0: K proj  -> bf16 [B,H,D,32]
// EPI 1: Q proj  -> bf16 [B,H,D,32], scaled by aux1[row]/sqrt(32)
// EPI 2: V proj  -> bf16 [B,H,32,D]
// EPI 3: GELU    -> bf16 [M,N], v = gelu(acc + aux1[col])
// EPI 4: RES     -> hb[row,col] += aux2[col]*(acc+aux1[col]) (fp32), C = bf16(new hb)
template <int EPI, int KT>
__global__ __launch_bounds__(256) void mgemm_k(const ushort* __restrict__ A,
                                               const ushort* __restrict__ Bw,
                                               ushort* __restrict__ C,
                                               int N,
                                               const float* __restrict__ aux1,
                                               const float* __restrict__ aux2,
                                               float* __restrict__ hb) {
  __shared__ ushort As[64 * 64];
  __shared__ ushort Bs[64 * 64];
  int tid = threadIdx.x;
  int w = tid >> 6, lane = tid & 63;
  int c = lane & 15, g = lane >> 4;
  int wr = w >> 1, wc = w & 1;
  int lr = lane >> 3, lsl = lane & 7;

  const ushort* Ab = A + (size_t)(blockIdx.y * 64) * KT;
  const ushort* Bb = Bw + (size_t)(blockIdx.x * 64) * KT;

  f4 acc[2][2] = {};

  for (int kt = 0; kt < KT / 64; kt++) {
    if (kt) __syncthreads();
    // stage A,B tiles: linear LDS dest, source slot pre-XOR-swizzled
    #pragma unroll
    for (int j = 0; j < 2; j++) {
      int rl = j * 32 + w * 8 + lr;
      int slot = lsl ^ (rl & 7);
      async_copy16(&As[(j * 32 + w * 8) * 64], Ab + (size_t)rl * KT + kt * 64 + slot * 8);
      async_copy16(&Bs[(j * 32 + w * 8) * 64], Bb + (size_t)rl * KT + kt * 64 + slot * 8);
    }
    __syncthreads();   // drains vmcnt(0) + barrier
    #pragma unroll
    for (int ks2 = 0; ks2 < 2; ks2++) {
      short8 af[2], bf_[2];
      #pragma unroll
      for (int mi = 0; mi < 2; mi++) {
        int rowl = wr * 32 + mi * 16 + c;
        int slot = (ks2 * 4 + g) ^ (rowl & 7);
        af[mi] = *(const short8*)&As[rowl * 64 + slot * 8];
      }
      #pragma unroll
      for (int ni = 0; ni < 2; ni++) {
        int rowl = wc * 32 + ni * 16 + c;
        int slot = (ks2 * 4 + g) ^ (rowl & 7);
        bf_[ni] = *(const short8*)&Bs[rowl * 64 + slot * 8];
      }
      #pragma unroll
      for (int mi = 0; mi < 2; mi++)
        #pragma unroll
        for (int ni = 0; ni < 2; ni++)
          acc[mi][ni] = __builtin_amdgcn_mfma_f32_16x16x32_bf16(af[mi], bf_[ni], acc[mi][ni], 0, 0, 0);
    }
  }

  // epilogue: D element (mi,ni,r) -> row = m0+mi*16+4g+r, col = n0+ni*16+c
  int m0 = blockIdx.y * 64 + wr * 32;
  int n0 = blockIdx.x * 64 + wc * 32;
  #pragma unroll
  for (int mi = 0; mi < 2; mi++) {
    #pragma unroll
    for (int ni = 0; ni < 2; ni++) {
      #pragma unroll
      for (int r = 0; r < 4; r++) {
        int row = m0 + mi * 16 + 4 * g + r;
        int col = n0 + ni * 16 + c;
        float v = acc[mi][ni][r];
        if (EPI == 0 || EPI == 1) {
          int bI = row >> 10, dI = row & 1023;
          int hI = col >> 5, eI = col & 31;
          float o = (EPI == 1) ? v * aux1[row] * 0.17677669529663687f : v;
          C[(((size_t)(bI * HH + hI)) * DD + dI) * HDD + eI] = f2bf(o);
        } else if (EPI == 2) {
          int bI = row >> 10, dI = row & 1023;
          int hI = col >> 5, eI = col & 31;
          C[(((size_t)(bI * HH + hI)) * HDD + eI) * DD + dI] = f2bf(v);
        } else if (EPI == 3) {
          v += aux1[col];
          float gl = 0.5f * v * (1.0f + erff(v * 0.70710678118654752f));
          C[(size_t)row * N + col] = f2bf(gl);
        } else if (EPI == 4) {
          v += aux1[col];
          size_t idx = (size_t)row * EE + col;
          float nh = hb[idx] + aux2[col] * v;
          hb[idx] = nh;
          C[idx] = f2bf(nh);
        }
      }
    }
  }
}

// ---------------- MFMA flash attention, diag-first + defer-max + window cut ----------------
// Qbf,Kbf: bf16 [B,H,D,32] (Q pre-scaled by qscale/sqrt(32)); Vtb: bf16 [B,H,32,D].
// grid (D/64, B*H), 256 threads = 4 waves, each wave owns 16 queries.
__global__ __launch_bounds__(256) void attn4_k(const ushort* __restrict__ Qbf,
                                               const ushort* __restrict__ Kbf,
                                               const ushort* __restrict__ Vtb,
                                               const float* __restrict__ gamma,
                                               const float* __restrict__ strength_p,
                                               float* __restrict__ h) {
  __shared__ __align__(16) ushort Pl[4][16][72];   // per-wave P tile, padded rows
  int tid = threadIdx.x;
  int w = tid >> 6, lane = tid & 63;
  int c = lane & 15, g = lane >> 4;
  int bh = blockIdx.y, b = bh >> 3, hh = bh & 7;
  int diag = blockIdx.x;
  int q0 = diag * 64 + w * 16;
  int qg = q0 + c;
  float ss = fmaxf(strength_p[0], 0.f) * exp2f(-(float)hh / 8.0f);
  const float L2E = 1.4426950408889634f;

  // Q fragment (B operand): lane holds Q[q0+c][8g..8g+7]
  short8 qf = *(const short8*)(Qbf + (((size_t)bh * DD + qg) << 5) + (g << 3));

  f4 oacc0 = {0.f, 0.f, 0.f, 0.f};
  f4 oacc1 = {0.f, 0.f, 0.f, 0.f};
  float mrun = -1e30f, lrun = 0.f;

  const ushort* Kb0 = Kbf + (((size_t)bh * DD + c) << 5) + (g << 3);
  const ushort* Vb0 = Vtb + ((size_t)(bh * HDD + c)) * DD + (g << 3);

  for (int kk = 0; kk < 16; kk++) {
    int ks = (diag + kk) & 15;
    if (kk) {
      // window cut: contribution bound exp(-ss*dmin) < e^-18 -> provably negligible
      int dmin = (ks > diag) ? (ks * 64 - (q0 + 15)) : (q0 - (ks * 64 + 63));
      if (ss * (float)dmin > 18.0f) continue;
    }
    // ---- QK^T (swapped): 4 tiles of 16 keys, S^T[k][q], full K=32 contraction ----
    f4 sa[4];
    #pragma unroll
    for (int t = 0; t < 4; t++) {
      short8 kf = *(const short8*)(Kb0 + (((size_t)(ks * 64 + t * 16)) << 5));
      f4 z = {0.f, 0.f, 0.f, 0.f};
      sa[t] = __builtin_amdgcn_mfma_f32_16x16x32_bf16(kf, qf, z, 0, 0, 0);
    }
    // ---- bias (lane owns query col c; key = ks*64 + t*16 + 4g + r) ----
    float s[16];
    if (kk == 0) {
      #pragma unroll
      for (int t = 0; t < 4; t++) {
        #pragma unroll
        for (int r = 0; r < 4; r++) {
          int k = ks * 64 + t * 16 + 4 * g + r;
          float ad = fabsf((float)(qg - k));
          s[t * 4 + r] = (k == qg) ? -1e30f : fmaf(-ss, ad, sa[t][r]);
        }
      }
    } else {
      float sgn = (ks > diag) ? -ss : ss;   // bias = sgn*(k - qg), always <= 0
      int kb = ks * 64 + 4 * g - qg;
      #pragma unroll
      for (int t = 0; t < 4; t++) {
        #pragma unroll
        for (int r = 0; r < 4; r++) {
          float dk = (float)(kb + t * 16 + r);
          s[t * 4 + r] = fmaf(sgn, dk, sa[t][r]);
        }
      }
    }
    // ---- max (tree; reduce across the 4 lanes sharing query c) ----
    float m01 = fmaxf(s[0], s[1]),  m23 = fmaxf(s[2], s[3]);
    float m45 = fmaxf(s[4], s[5]),  m67 = fmaxf(s[6], s[7]);
    float m89 = fmaxf(s[8], s[9]),  mab = fmaxf(s[10], s[11]);
    float mcd = fmaxf(s[12], s[13]), mef = fmaxf(s[14], s[15]);
    float mloc = fmaxf(fmaxf(fmaxf(m01, m23), fmaxf(m45, m67)),
                       fmaxf(fmaxf(m89, mab), fmaxf(mcd, mef)));
    mloc = fmaxf(mloc, __shfl_xor(mloc, 16));
    mloc = fmaxf(mloc, __shfl_xor(mloc, 32));
    // ---- defer-max: exact skip when running max unchanged ----
    if (__any(mloc > mrun)) {
      float mnew = fmaxf(mrun, mloc);
      float sc_ = exp2f((mrun - mnew) * L2E);
      mrun = mnew;
      lrun *= sc_;
      #pragma unroll
      for (int r = 0; r < 4; r++) {
        float sq = __shfl(sc_, 4 * g + r);
        oacc0[r] *= sq;
        oacc1[r] *= sq;
      }
    }
    // ---- exp + sum + truncated bf16 pack ----
    float mL = mrun * L2E;
    float ll = 0.f;
    #pragma unroll
    for (int i = 0; i < 16; i++) {
      float p = exp2f(fmaf(s[i], L2E, -mL));
      s[i] = p;
      ll += p;
    }
    ll += __shfl_xor(ll, 16);
    ll += __shfl_xor(ll, 32);
    lrun += ll;
    #pragma unroll
    for (int t = 0; t < 4; t++) {
      uint2 u;
      u.x = __builtin_amdgcn_perm(__float_as_uint(s[t * 4 + 1]), __float_as_uint(s[t * 4 + 0]), 0x07060302u);
      u.y = __builtin_amdgcn_perm(__float_as_uint(s[t * 4 + 3]), __float_as_uint(s[t * 4 + 2]), 0x07060302u);
      *(uint2*)&Pl[w][c][t * 16 + 4 * g] = u;
    }
    // ---- PV: O[q][e] += P[q][k] V[k][e], two K=32 halves, two e-tiles ----
    #pragma unroll
    for (int hb2 = 0; hb2 < 2; hb2++) {
      short8 pa = *(const short8*)&Pl[w][c][hb2 * 32 + 8 * g];
      short8 v0 = *(const short8*)(Vb0 + ks * 64 + hb2 * 32);
      short8 v1 = *(const short8*)(Vb0 + (size_t)16 * DD + ks * 64 + hb2 * 32);
      oacc0 = __builtin_amdgcn_mfma_f32_16x16x32_bf16(pa, v0, oacc0, 0, 0, 0);
      oacc1 = __builtin_amdgcn_mfma_f32_16x16x32_bf16(pa, v1, oacc1, 0, 0, 0);
    }
  }

  // ---- epilogue: h += gamma * O / l ----
  float linv = 1.0f / lrun;
  #pragma unroll
  for (int r = 0; r < 4; r++) {
    float li = __shfl(linv, 4 * g + r);
    int q = q0 + 4 * g + r;
    size_t base = ((size_t)(b * DD + q)) * EE + hh * HDD;
    int e0 = c, e1 = 16 + c;
    h[base + e0] += gamma[hh * HDD + e0] * oacc0[r] * li;
    h[base + e1] += gamma[hh * HDD + e1] * oacc1[r] * li;
  }
}

// ---------------- LayerNorm over rows of 256 -> bf16 ----------------
__global__ __launch_bounds__(256) void ln_k(const float* __restrict__ hin,
                                            const float* __restrict__ w,
                                            const float* __restrict__ bb,
                                            ushort* __restrict__ y) {
  __shared__ float red[256];
  int r = blockIdx.x, t = threadIdx.x;
  float v = hin[(size_t)r * EE + t];
  red[t] = v; __syncthreads();
  for (int off = 128; off; off >>= 1) {
    if (t < off) red[t] += red[t + off];
    __syncthreads();
  }
  float mean = red[0] / (float)EE;
  __syncthreads();
  float dv = v - mean;
  red[t] = dv * dv; __syncthreads();
  for (int off = 128; off; off >>= 1) {
    if (t < off) red[t] += red[t + off];
    __syncthreads();
  }
  float var = red[0] / (float)EE;
  y[(size_t)r * EE + t] = f2bf(dv * rsqrtf(var + 1e-5f) * w[t] + bb[t]);
}

// ---------------- final projection to scalar per row ----------------
__global__ __launch_bounds__(256) void out_k(const ushort* __restrict__ t_,
                                             const float* __restrict__ w2,
                                             const float* __restrict__ b2,
                                             float* __restrict__ out) {
  int w = threadIdx.x >> 6, lane = threadIdx.x & 63;
  int r = blockIdx.x * 4 + w;
  float s = 0.f;
  #pragma unroll
  for (int i = 0; i < 4; i++) s += bf2f(t_[(size_t)r * EE + lane + i * 64]) * w2[lane + i * 64];
  #pragma unroll
  for (int off = 32; off; off >>= 1) s += __shfl_xor(s, off);
  if (lane == 0) out[r] = s + b2[0];
}

extern "C" void kernel_launch(void* const* d_in, const int* in_sizes, int n_in,
                              void* d_out, int out_size, void* d_ws, size_t ws_size,
                              hipStream_t stream) {
  const float* x            = (const float*)d_in[0];
  const float* value_w      = (const float*)d_in[1];
  const float* value_b      = (const float*)d_in[2];
  const float* feature_embed= (const float*)d_in[3];
  const float* binary_w     = (const float*)d_in[4];
  const float* qw           = (const float*)d_in[5];
  const float* kw           = (const float*)d_in[6];
  const float* vw           = (const float*)d_in[7];
  const float* film_alpha   = (const float*)d_in[8];
  const float* film_a       = (const float*)d_in[9];
  const float* ln1_w        = (const float*)d_in[10];
  const float* ln1_b        = (const float*)d_in[11];
  const float* ffn_w1       = (const float*)d_in[12];
  const float* ffn_b1       = (const float*)d_in[13];
  const float* ffn_w2       = (const float*)d_in[14];
  const float* ffn_b2       = (const float*)d_in[15];
  const float* gamma_attn   = (const float*)d_in[16];
  const float* gamma_ffn    = (const float*)d_in[17];
  const float* corr_ln_w    = (const float*)d_in[18];
  const float* corr_ln_b    = (const float*)d_in[19];
  const float* corr_w1      = (const float*)d_in[20];
  const float* corr_b1      = (const float*)d_in[21];
  const float* corr_w2      = (const float*)d_in[22];
  const float* corr_b2      = (const float*)d_in[23];
  const float* alibi_strength=(const float*)d_in[24];

  const size_t ME = (size_t)BD * DD * EE;   // 2M
  float* ws = (float*)d_ws;
  float* pos    = ws;                       // 262144 f
  float* qscale = pos + DD * EE;            // 8192 f
  float* hb     = qscale + BD * DD;         // 2M f
  ushort* kv_bf = (ushort*)(hb + ME);       // 2M us
  ushort* hb_bf = kv_bf + ME;               // 2M us
  ushort* yb_bf = hb_bf + ME;               // 2M us
  ushort* tb_bf = yb_bf + ME;               // 4M us
  ushort* Qbf   = tb_bf + 2 * ME;           // 2M us
  ushort* Kbf   = Qbf + ME;                 // 2M us
  ushort* Vtb   = Kbf + ME;                 // 2M us
  ushort* wbf   = Vtb + ME;                 // 524288 us
  ushort* qwb   = wbf;
  ushort* kwb   = wbf + 65536;
  ushort* vwb   = wbf + 131072;
  ushort* w1b   = wbf + 196608;
  ushort* w2b   = wbf + 327680;
  ushort* cw1b  = wbf + 458752;

  const int M = BD * DD;   // 8192

  k_qscale<<<BD, 256, 0, stream>>>(x, film_alpha, film_a, qscale);
  k_pos<<<DD, 256, 0, stream>>>(feature_embed, binary_w, pos);
  k_kvh<<<(BD * DD * EE) / 256, 256, 0, stream>>>(x, value_w, value_b, pos, kv_bf, hb, hb_bf);
  k_wconv<<<524288 / 256, 256, 0, stream>>>(qw, kw, vw, ffn_w1, ffn_w2, corr_w1, wbf);

  mgemm_k<0, 256><<<dim3(EE / 64, M / 64), 256, 0, stream>>>(kv_bf, kwb, Kbf, EE, nullptr, nullptr, nullptr);
  mgemm_k<2, 256><<<dim3(EE / 64, M / 64), 256, 0, stream>>>(kv_bf, vwb, Vtb, EE, nullptr, nullptr, nullptr);

  for (int layer = 0; layer < 2; layer++) {
    mgemm_k<1, 256><<<dim3(EE / 64, M / 64), 256, 0, stream>>>(hb_bf, qwb, Qbf, EE, qscale, nullptr, nullptr);
    attn4_k<<<dim3(DD / 64, BD * HH), 256, 0, stream>>>(Qbf, Kbf, Vtb, gamma_attn, alibi_strength, hb);
    ln_k<<<M, 256, 0, stream>>>(hb, ln1_w, ln1_b, yb_bf);
    mgemm_k<3, 256><<<dim3((2 * EE) / 64, M / 64), 256, 0, stream>>>(yb_bf, w1b, tb_bf, 2 * EE, ffn_b1, nullptr, nullptr);
    mgemm_k<4, 512><<<dim3(EE / 64, M / 64), 256, 0, stream>>>(tb_bf, w2b, hb_bf, EE, ffn_b2, gamma_ffn, hb);
  }

  ln_k<<<M, 256, 0, stream>>>(hb, corr_ln_w, corr_ln_b, yb_bf);
  mgemm_k<3, 256><<<dim3(EE / 64, M / 64), 256, 0, stream>>>(yb_bf, cw1b, tb_bf, EE, corr_b1, nullptr, nullptr);
  out_k<<<M / 4, 256, 0, stream>>>(tb_bf, corr_w2, corr_b2, (float*)d_out);
}

// Round 6
// 177.135 us; speedup vs baseline: 15.4632x; 1.1163x over previous
//
#include <hip/hip_runtime.h>
#include <math.h>

#define BD 8
#define DD 1024
#define EE 256
#define HH 8
#define HDD 32
#define NBITS 11

typedef __attribute__((ext_vector_type(8))) short short8;
typedef __attribute__((ext_vector_type(4))) float f4;

__device__ __forceinline__ ushort f2bf(float f) {
  unsigned u = __float_as_uint(f);
  u += 0x7fffu + ((u >> 16) & 1u);
  return (ushort)(u >> 16);
}
__device__ __forceinline__ float bf2f(ushort u) {
  return __uint_as_float(((unsigned)u) << 16);
}
__device__ __forceinline__ void async_copy16(ushort* lds, const ushort* g) {
  __builtin_amdgcn_global_load_lds((const __attribute__((address_space(1))) void*)g,
                                   (__attribute__((address_space(3))) void*)lds, 16, 0, 0);
}

// ---------------- q_scale: FiLM gain from neighbor mean ----------------
__global__ __launch_bounds__(256) void k_qscale(const float* __restrict__ x,
                                                const float* __restrict__ film_alpha,
                                                const float* __restrict__ film_a,
                                                float* __restrict__ qscale) {
  __shared__ float red[256];
  int b = blockIdx.x, t = threadIdx.x;
  float s = 0.f;
  #pragma unroll
  for (int i = 0; i < 4; i++) s += x[b * DD + t + i * 256];
  red[t] = s; __syncthreads();
  for (int off = 128; off > 0; off >>= 1) {
    if (t < off) red[t] += red[t + off];
    __syncthreads();
  }
  float total = red[0];
  float ta = tanhf(film_alpha[0]);
  float fa = film_a[0];
  #pragma unroll
  for (int i = 0; i < 4; i++) {
    int d = t + i * 256;
    float xn = (total - x[b * DD + d]) / 1023.0f;
    float qs = 1.0f + ta * tanhf(fa * xn);
    qs = fminf(fmaxf(qs, 0.7f), 1.3f);
    qscale[b * DD + d] = qs;
  }
}

// ---------------- pos = feature_embed + codes @ binary_w.T ----------------
__global__ __launch_bounds__(256) void k_pos(const float* __restrict__ fe,
                                             const float* __restrict__ binary_w,
                                             float* __restrict__ pos) {
  int d = blockIdx.x, e = threadIdx.x;
  float s = fe[d * EE + e];
  int code = d + 1;
  #pragma unroll
  for (int bit = 0; bit < NBITS; bit++) {
    float cb = (float)((code >> (NBITS - 1 - bit)) & 1) - 0.5f;
    s += cb * binary_w[e * NBITS + bit];
  }
  pos[d * EE + e] = s;
}

// ---------------- kv/h init: kv_bf = bf16(x*vw+vb+pos); h=pos; h_bf=bf16(pos) ----------------
__global__ __launch_bounds__(256) void k_kvh(const float* __restrict__ x,
                                             const float* __restrict__ value_w,
                                             const float* __restrict__ value_b,
                                             const float* __restrict__ pos,
                                             ushort* __restrict__ kv_bf,
                                             float* __restrict__ h,
                                             ushort* __restrict__ h_bf) {
  int idx = blockIdx.x * 256 + threadIdx.x;   // over B*D*E = 2M
  int e = idx & (EE - 1);
  int d = (idx >> 8) & (DD - 1);
  int b = idx >> 18;
  float p = pos[(idx & (DD * EE - 1))];
  kv_bf[idx] = f2bf(x[b * DD + d] * value_w[e] + value_b[e] + p);
  h[idx] = p;
  h_bf[idx] = f2bf(p);
}

// ---------------- weights -> bf16 (one launch) ----------------
// layout: qw[65536] kw[65536] vw[65536] w1[131072] w2[131072] cw1[65536]
__global__ __launch_bounds__(256) void k_wconv(const float* __restrict__ qw,
                                               const float* __restrict__ kw,
                                               const float* __restrict__ vw,
                                               const float* __restrict__ w1,
                                               const float* __restrict__ w2,
                                               const float* __restrict__ cw1,
                                               ushort* __restrict__ o) {
  int i = blockIdx.x * 256 + threadIdx.x;
  float v;
  if (i < 65536) v = qw[i];
  else if (i < 131072) v = kw[i - 65536];
  else if (i < 196608) v = vw[i - 131072];
  else if (i < 327680) v = w1[i - 196608];
  else if (i < 458752) v = w2[i - 327680];
  else v = cw1[i - 458752];
  o[i] = f2bf(v);
}

// ---------------- MFMA GEMM: C[M,N] = A[M,K] @ W[N,K]^T, bf16 in / fp32 acc ----------------
// 64x64 tile, BK=64, 4 waves (2x2), wave tile 32x32.
// EPI 0: K proj  -> bf16 [B,H,D,32]
// EPI 1: Q proj  -> bf16 [B,H,D,32], scaled by aux1[row]/sqrt(32)
// EPI 2: V proj  -> bf16 [B,H,32,D]
// EPI 3: GELU    -> bf16 [M,N], v = gelu(acc + aux1[col])
// EPI 4: RES     -> hb[row,col] += aux2[col]*(acc+aux1[col]) (fp32), C = bf16(new hb)
template <int EPI, int KT>
__global__ __launch_bounds__(256) void mgemm_k(const ushort* __restrict__ A,
                                               const ushort* __restrict__ Bw,
                                               ushort* __restrict__ C,
                                               int N,
                                               const float* __restrict__ aux1,
                                               const float* __restrict__ aux2,
                                               float* __restrict__ hb) {
  __shared__ ushort As[64 * 64];
  __shared__ ushort Bs[64 * 64];
  int tid = threadIdx.x;
  int w = tid >> 6, lane = tid & 63;
  int c = lane & 15, g = lane >> 4;
  int wr = w >> 1, wc = w & 1;
  int lr = lane >> 3, lsl = lane & 7;

  const ushort* Ab = A + (size_t)(blockIdx.y * 64) * KT;
  const ushort* Bb = Bw + (size_t)(blockIdx.x * 64) * KT;

  f4 acc[2][2] = {};

  for (int kt = 0; kt < KT / 64; kt++) {
    if (kt) __syncthreads();
    // stage A,B tiles: linear LDS dest, source slot pre-XOR-swizzled
    #pragma unroll
    for (int j = 0; j < 2; j++) {
      int rl = j * 32 + w * 8 + lr;
      int slot = lsl ^ (rl & 7);
      async_copy16(&As[(j * 32 + w * 8) * 64], Ab + (size_t)rl * KT + kt * 64 + slot * 8);
      async_copy16(&Bs[(j * 32 + w * 8) * 64], Bb + (size_t)rl * KT + kt * 64 + slot * 8);
    }
    __syncthreads();   // drains vmcnt(0) + barrier
    #pragma unroll
    for (int ks2 = 0; ks2 < 2; ks2++) {
      short8 af[2], bf_[2];
      #pragma unroll
      for (int mi = 0; mi < 2; mi++) {
        int rowl = wr * 32 + mi * 16 + c;
        int slot = (ks2 * 4 + g) ^ (rowl & 7);
        af[mi] = *(const short8*)&As[rowl * 64 + slot * 8];
      }
      #pragma unroll
      for (int ni = 0; ni < 2; ni++) {
        int rowl = wc * 32 + ni * 16 + c;
        int slot = (ks2 * 4 + g) ^ (rowl & 7);
        bf_[ni] = *(const short8*)&Bs[rowl * 64 + slot * 8];
      }
      #pragma unroll
      for (int mi = 0; mi < 2; mi++)
        #pragma unroll
        for (int ni = 0; ni < 2; ni++)
          acc[mi][ni] = __builtin_amdgcn_mfma_f32_16x16x32_bf16(af[mi], bf_[ni], acc[mi][ni], 0, 0, 0);
    }
  }

  // epilogue: D element (mi,ni,r) -> row = m0+mi*16+4g+r, col = n0+ni*16+c
  int m0 = blockIdx.y * 64 + wr * 32;
  int n0 = blockIdx.x * 64 + wc * 32;
  #pragma unroll
  for (int mi = 0; mi < 2; mi++) {
    #pragma unroll
    for (int ni = 0; ni < 2; ni++) {
      #pragma unroll
      for (int r = 0; r < 4; r++) {
        int row = m0 + mi * 16 + 4 * g + r;
        int col = n0 + ni * 16 + c;
        float v = acc[mi][ni][r];
        if (EPI == 0 || EPI == 1) {
          int bI = row >> 10, dI = row & 1023;
          int hI = col >> 5, eI = col & 31;
          float o = (EPI == 1) ? v * aux1[row] * 0.17677669529663687f : v;
          C[(((size_t)(bI * HH + hI)) * DD + dI) * HDD + eI] = f2bf(o);
        } else if (EPI == 2) {
          int bI = row >> 10, dI = row & 1023;
          int hI = col >> 5, eI = col & 31;
          C[(((size_t)(bI * HH + hI)) * HDD + eI) * DD + dI] = f2bf(v);
        } else if (EPI == 3) {
          v += aux1[col];
          float gl = 0.5f * v * (1.0f + erff(v * 0.70710678118654752f));
          C[(size_t)row * N + col] = f2bf(gl);
        } else if (EPI == 4) {
          v += aux1[col];
          size_t idx = (size_t)row * EE + col;
          float nh = hb[idx] + aux2[col] * v;
          hb[idx] = nh;
          C[idx] = f2bf(nh);
        }
      }
    }
  }
}

// ---------------- MFMA flash attention v5: XCD-swizzled + static softmax + window cut ----------------
// Qbf,Kbf: bf16 [B,H,D,32] (Q pre-scaled by qscale/sqrt(32)); Vtb: bf16 [B,H,32,D].
// 1D grid of 1024; logical id swizzled so all 16 q-blocks of a (b,h) share an XCD
// (K/V panels stay L2-resident). Scores provably tiny (|qk|<<1, bias<=0) -> fixed
// softmax reference point m=0: no max tracking, no rescale, l-reduce once at end.
__global__ __launch_bounds__(256) void attn5_k(const ushort* __restrict__ Qbf,
                                               const ushort* __restrict__ Kbf,
                                               const ushort* __restrict__ Vtb,
                                               const float* __restrict__ gamma,
                                               const float* __restrict__ strength_p,
                                               float* __restrict__ h) {
  __shared__ __align__(16) ushort Pl[4][16][72];   // per-wave P tile, padded rows
  int tid = threadIdx.x;
  int w = tid >> 6, lane = tid & 63;
  int c = lane & 15, g = lane >> 4;
  // XCD-aware bijective swizzle: hw blocks {i : i%8==x} -> logical chunk x*128..
  int lid = (blockIdx.x & 7) * 128 + (blockIdx.x >> 3);
  int bh = lid >> 4;
  int diag = lid & 15;
  int b = bh >> 3, hh = bh & 7;
  int q0 = diag * 64 + w * 16;
  int qg = q0 + c;
  float ss = fmaxf(strength_p[0], 0.f) * exp2f(-(float)hh / 8.0f);
  const float L2E = 1.4426950408889634f;

  // Q fragment (B operand): lane holds Q[q0+c][8g..8g+7]
  short8 qf = *(const short8*)(Qbf + (((size_t)bh * DD + qg) << 5) + (g << 3));

  f4 oacc0 = {0.f, 0.f, 0.f, 0.f};
  f4 oacc1 = {0.f, 0.f, 0.f, 0.f};
  float lpart = 0.f;

  const ushort* Kb0 = Kbf + (((size_t)bh * DD + c) << 5) + (g << 3);
  const ushort* Vb0 = Vtb + ((size_t)(bh * HDD + c)) * DD + (g << 3);

  for (int kk = 0; kk < 16; kk++) {
    int ks = (diag + kk) & 15;
    if (kk) {
      // window cut: relative contribution bound < e^-14 -> negligible
      int dmin = (ks > diag) ? (ks * 64 - (q0 + 15)) : (q0 - (ks * 64 + 63));
      if (ss * (float)dmin > 14.0f) continue;
    }
    // ---- QK^T (swapped): 4 tiles of 16 keys, S^T[k][q], full K=32 contraction ----
    f4 sa[4];
    #pragma unroll
    for (int t = 0; t < 4; t++) {
      short8 kf = *(const short8*)(Kb0 + (((size_t)(ks * 64 + t * 16)) << 5));
      f4 z = {0.f, 0.f, 0.f, 0.f};
      sa[t] = __builtin_amdgcn_mfma_f32_16x16x32_bf16(kf, qf, z, 0, 0, 0);
    }
    // ---- bias (lane owns query col c; key = ks*64 + t*16 + 4g + r) ----
    float s[16];
    if (kk == 0) {
      #pragma unroll
      for (int t = 0; t < 4; t++) {
        #pragma unroll
        for (int r = 0; r < 4; r++) {
          int k = ks * 64 + t * 16 + 4 * g + r;
          float ad = fabsf((float)(qg - k));
          s[t * 4 + r] = (k == qg) ? -1e30f : fmaf(-ss, ad, sa[t][r]);
        }
      }
    } else {
      float sgn = (ks > diag) ? -ss : ss;   // bias = sgn*(k - qg), always <= 0
      int kb = ks * 64 + 4 * g - qg;
      #pragma unroll
      for (int t = 0; t < 4; t++) {
        #pragma unroll
        for (int r = 0; r < 4; r++) {
          float dk = (float)(kb + t * 16 + r);
          s[t * 4 + r] = fmaf(sgn, dk, sa[t][r]);
        }
      }
    }
    // ---- static-reference exp + per-lane partial sum + truncated bf16 pack ----
    #pragma unroll
    for (int i = 0; i < 16; i++) {
      float p = exp2f(s[i] * L2E);
      s[i] = p;
      lpart += p;
    }
    #pragma unroll
    for (int t = 0; t < 4; t++) {
      uint2 u;
      u.x = __builtin_amdgcn_perm(__float_as_uint(s[t * 4 + 1]), __float_as_uint(s[t * 4 + 0]), 0x07060302u);
      u.y = __builtin_amdgcn_perm(__float_as_uint(s[t * 4 + 3]), __float_as_uint(s[t * 4 + 2]), 0x07060302u);
      *(uint2*)&Pl[w][c][t * 16 + 4 * g] = u;
    }
    // ---- PV: O[q][e] += P[q][k] V[k][e], two K=32 halves, two e-tiles ----
    #pragma unroll
    for (int hb2 = 0; hb2 < 2; hb2++) {
      short8 pa = *(const short8*)&Pl[w][c][hb2 * 32 + 8 * g];
      short8 v0 = *(const short8*)(Vb0 + ks * 64 + hb2 * 32);
      short8 v1 = *(const short8*)(Vb0 + (size_t)16 * DD + ks * 64 + hb2 * 32);
      oacc0 = __builtin_amdgcn_mfma_f32_16x16x32_bf16(pa, v0, oacc0, 0, 0, 0);
      oacc1 = __builtin_amdgcn_mfma_f32_16x16x32_bf16(pa, v1, oacc1, 0, 0, 0);
    }
  }

  // ---- l reduce across the 4 lanes sharing query c (done once, not per step) ----
  lpart += __shfl_xor(lpart, 16);
  lpart += __shfl_xor(lpart, 32);
  float linv = 1.0f / lpart;

  // ---- epilogue: h += gamma * O / l ----
  #pragma unroll
  for (int r = 0; r < 4; r++) {
    float li = __shfl(linv, 4 * g + r);
    int q = q0 + 4 * g + r;
    size_t base = ((size_t)(b * DD + q)) * EE + hh * HDD;
    int e0 = c, e1 = 16 + c;
    h[base + e0] += gamma[hh * HDD + e0] * oacc0[r] * li;
    h[base + e1] += gamma[hh * HDD + e1] * oacc1[r] * li;
  }
}

// ---------------- LayerNorm over rows of 256 -> bf16 ----------------
__global__ __launch_bounds__(256) void ln_k(const float* __restrict__ hin,
                                            const float* __restrict__ w,
                                            const float* __restrict__ bb,
                                            ushort* __restrict__ y) {
  __shared__ float red[256];
  int r = blockIdx.x, t = threadIdx.x;
  float v = hin[(size_t)r * EE + t];
  red[t] = v; __syncthreads();
  for (int off = 128; off; off >>= 1) {
    if (t < off) red[t] += red[t + off];
    __syncthreads();
  }
  float mean = red[0] / (float)EE;
  __syncthreads();
  float dv = v - mean;
  red[t] = dv * dv; __syncthreads();
  for (int off = 128; off; off >>= 1) {
    if (t < off) red[t] += red[t + off];
    __syncthreads();
  }
  float var = red[0] / (float)EE;
  y[(size_t)r * EE + t] = f2bf(dv * rsqrtf(var + 1e-5f) * w[t] + bb[t]);
}

// ---------------- final projection to scalar per row ----------------
__global__ __launch_bounds__(256) void out_k(const ushort* __restrict__ t_,
                                             const float* __restrict__ w2,
                                             const float* __restrict__ b2,
                                             float* __restrict__ out) {
  int w = threadIdx.x >> 6, lane = threadIdx.x & 63;
  int r = blockIdx.x * 4 + w;
  float s = 0.f;
  #pragma unroll
  for (int i = 0; i < 4; i++) s += bf2f(t_[(size_t)r * EE + lane + i * 64]) * w2[lane + i * 64];
  #pragma unroll
  for (int off = 32; off; off >>= 1) s += __shfl_xor(s, off);
  if (lane == 0) out[r] = s + b2[0];
}

extern "C" void kernel_launch(void* const* d_in, const int* in_sizes, int n_in,
                              void* d_out, int out_size, void* d_ws, size_t ws_size,
                              hipStream_t stream) {
  const float* x            = (const float*)d_in[0];
  const float* value_w      = (const float*)d_in[1];
  const float* value_b      = (const float*)d_in[2];
  const float* feature_embed= (const float*)d_in[3];
  const float* binary_w     = (const float*)d_in[4];
  const float* qw           = (const float*)d_in[5];
  const float* kw           = (const float*)d_in[6];
  const float* vw           = (const float*)d_in[7];
  const float* film_alpha   = (const float*)d_in[8];
  const float* film_a       = (const float*)d_in[9];
  const float* ln1_w        = (const float*)d_in[10];
  const float* ln1_b        = (const float*)d_in[11];
  const float* ffn_w1       = (const float*)d_in[12];
  const float* ffn_b1       = (const float*)d_in[13];
  const float* ffn_w2       = (const float*)d_in[14];
  const float* ffn_b2       = (const float*)d_in[15];
  const float* gamma_attn   = (const float*)d_in[16];
  const float* gamma_ffn    = (const float*)d_in[17];
  const float* corr_ln_w    = (const float*)d_in[18];
  const float* corr_ln_b    = (const float*)d_in[19];
  const float* corr_w1      = (const float*)d_in[20];
  const float* corr_b1      = (const float*)d_in[21];
  const float* corr_w2      = (const float*)d_in[22];
  const float* corr_b2      = (const float*)d_in[23];
  const float* alibi_strength=(const float*)d_in[24];

  const size_t ME = (size_t)BD * DD * EE;   // 2M
  float* ws = (float*)d_ws;
  float* pos    = ws;                       // 262144 f
  float* qscale = pos + DD * EE;            // 8192 f
  float* hb     = qscale + BD * DD;         // 2M f
  ushort* kv_bf = (ushort*)(hb + ME);       // 2M us
  ushort* hb_bf = kv_bf + ME;               // 2M us
  ushort* yb_bf = hb_bf + ME;               // 2M us
  ushort* tb_bf = yb_bf + ME;               // 4M us
  ushort* Qbf   = tb_bf + 2 * ME;           // 2M us
  ushort* Kbf   = Qbf + ME;                 // 2M us
  ushort* Vtb   = Kbf + ME;                 // 2M us
  ushort* wbf   = Vtb + ME;                 // 524288 us
  ushort* qwb   = wbf;
  ushort* kwb   = wbf + 65536;
  ushort* vwb   = wbf + 131072;
  ushort* w1b   = wbf + 196608;
  ushort* w2b   = wbf + 327680;
  ushort* cw1b  = wbf + 458752;

  const int M = BD * DD;   // 8192

  k_qscale<<<BD, 256, 0, stream>>>(x, film_alpha, film_a, qscale);
  k_pos<<<DD, 256, 0, stream>>>(feature_embed, binary_w, pos);
  k_kvh<<<(BD * DD * EE) / 256, 256, 0, stream>>>(x, value_w, value_b, pos, kv_bf, hb, hb_bf);
  k_wconv<<<524288 / 256, 256, 0, stream>>>(qw, kw, vw, ffn_w1, ffn_w2, corr_w1, wbf);

  mgemm_k<0, 256><<<dim3(EE / 64, M / 64), 256, 0, stream>>>(kv_bf, kwb, Kbf, EE, nullptr, nullptr, nullptr);
  mgemm_k<2, 256><<<dim3(EE / 64, M / 64), 256, 0, stream>>>(kv_bf, vwb, Vtb, EE, nullptr, nullptr, nullptr);

  for (int layer = 0; layer < 2; layer++) {
    mgemm_k<1, 256><<<dim3(EE / 64, M / 64), 256, 0, stream>>>(hb_bf, qwb, Qbf, EE, qscale, nullptr, nullptr);
    attn5_k<<<dim3(BD * HH * (DD / 64)), 256, 0, stream>>>(Qbf, Kbf, Vtb, gamma_attn, alibi_strength, hb);
    ln_k<<<M, 256, 0, stream>>>(hb, ln1_w, ln1_b, yb_bf);
    mgemm_k<3, 256><<<dim3((2 * EE) / 64, M / 64), 256, 0, stream>>>(yb_bf, w1b, tb_bf, 2 * EE, ffn_b1, nullptr, nullptr);
    mgemm_k<4, 512><<<dim3(EE / 64, M / 64), 256, 0, stream>>>(tb_bf, w2b, hb_bf, EE, ffn_b2, gamma_ffn, hb);
  }

  ln_k<<<M, 256, 0, stream>>>(hb, corr_ln_w, corr_ln_b, yb_bf);
  mgemm_k<3, 256><<<dim3(EE / 64, M / 64), 256, 0, stream>>>(yb_bf, cw1b, tb_bf, EE, corr_b1, nullptr, nullptr);
  out_k<<<M / 4, 256, 0, stream>>>(tb_bf, corr_w2, corr_b2, (float*)d_out);
}

// Round 7
// 176.661 us; speedup vs baseline: 15.5047x; 1.0027x over previous
//
#include <hip/hip_runtime.h>
#include <math.h>

#define BD 8
#define DD 1024
#define EE 256
#define HH 8
#define HDD 32
#define NBITS 11

typedef __attribute__((ext_vector_type(8))) short short8;
typedef __attribute__((ext_vector_type(4))) float f4;

__device__ __forceinline__ ushort f2bf(float f) {
  unsigned u = __float_as_uint(f);
  u += 0x7fffu + ((u >> 16) & 1u);
  return (ushort)(u >> 16);
}
__device__ __forceinline__ float bf2f(ushort u) {
  return __uint_as_float(((unsigned)u) << 16);
}
__device__ __forceinline__ void async_copy16(ushort* lds, const ushort* g) {
  __builtin_amdgcn_global_load_lds((const __attribute__((address_space(1))) void*)g,
                                   (__attribute__((address_space(3))) void*)lds, 16, 0, 0);
}

// ---------------- q_scale: FiLM gain from neighbor mean ----------------
__global__ __launch_bounds__(256) void k_qscale(const float* __restrict__ x,
                                                const float* __restrict__ film_alpha,
                                                const float* __restrict__ film_a,
                                                float* __restrict__ qscale) {
  __shared__ float red[256];
  int b = blockIdx.x, t = threadIdx.x;
  float s = 0.f;
  #pragma unroll
  for (int i = 0; i < 4; i++) s += x[b * DD + t + i * 256];
  red[t] = s; __syncthreads();
  for (int off = 128; off > 0; off >>= 1) {
    if (t < off) red[t] += red[t + off];
    __syncthreads();
  }
  float total = red[0];
  float ta = tanhf(film_alpha[0]);
  float fa = film_a[0];
  #pragma unroll
  for (int i = 0; i < 4; i++) {
    int d = t + i * 256;
    float xn = (total - x[b * DD + d]) / 1023.0f;
    float qs = 1.0f + ta * tanhf(fa * xn);
    qs = fminf(fmaxf(qs, 0.7f), 1.3f);
    qscale[b * DD + d] = qs;
  }
}

// ---------------- pos = feature_embed + codes @ binary_w.T ----------------
__global__ __launch_bounds__(256) void k_pos(const float* __restrict__ fe,
                                             const float* __restrict__ binary_w,
                                             float* __restrict__ pos) {
  int d = blockIdx.x, e = threadIdx.x;
  float s = fe[d * EE + e];
  int code = d + 1;
  #pragma unroll
  for (int bit = 0; bit < NBITS; bit++) {
    float cb = (float)((code >> (NBITS - 1 - bit)) & 1) - 0.5f;
    s += cb * binary_w[e * NBITS + bit];
  }
  pos[d * EE + e] = s;
}

// ---------------- kv/h init: kv_bf = bf16(x*vw+vb+pos); h=pos; h_bf=bf16(pos) ----------------
__global__ __launch_bounds__(256) void k_kvh(const float* __restrict__ x,
                                             const float* __restrict__ value_w,
                                             const float* __restrict__ value_b,
                                             const float* __restrict__ pos,
                                             ushort* __restrict__ kv_bf,
                                             float* __restrict__ h,
                                             ushort* __restrict__ h_bf) {
  int idx = blockIdx.x * 256 + threadIdx.x;   // over B*D*E = 2M
  int e = idx & (EE - 1);
  int d = (idx >> 8) & (DD - 1);
  int b = idx >> 18;
  float p = pos[(idx & (DD * EE - 1))];
  kv_bf[idx] = f2bf(x[b * DD + d] * value_w[e] + value_b[e] + p);
  h[idx] = p;
  h_bf[idx] = f2bf(p);
}

// ---------------- weights -> bf16 (one launch) ----------------
// layout: qw[65536] kw[65536] vw[65536] w1[131072] w2[131072] cw1[65536]
__global__ __launch_bounds__(256) void k_wconv(const float* __restrict__ qw,
                                               const float* __restrict__ kw,
                                               const float* __restrict__ vw,
                                               const float* __restrict__ w1,
                                               const float* __restrict__ w2,
                                               const float* __restrict__ cw1,
                                               ushort* __restrict__ o) {
  int i = blockIdx.x * 256 + threadIdx.x;
  float v;
  if (i < 65536) v = qw[i];
  else if (i < 131072) v = kw[i - 65536];
  else if (i < 196608) v = vw[i - 131072];
  else if (i < 327680) v = w1[i - 196608];
  else if (i < 458752) v = w2[i - 327680];
  else v = cw1[i - 458752];
  o[i] = f2bf(v);
}

// ---------------- MFMA GEMM: C[M,N] = A[M,K] @ W[N,K]^T, bf16 in / fp32 acc ----------------
// 64x64 tile, BK=64, 4 waves (2x2), wave tile 32x32.
// EPI 0: K proj  -> bf16 [B,H,D,32]
// EPI 1: Q proj  -> bf16 [B,H,D,32], scaled by aux1[row]/sqrt(32)
// EPI 2: V proj  -> bf16 [B,H,32,D]
// EPI 3: GELU    -> bf16 [M,N], v = gelu(acc + aux1[col])
// EPI 4: RES     -> hb[row,col] += aux2[col]*(acc+aux1[col]) (fp32), C = bf16(new hb)
template <int EPI, int KT>
__global__ __launch_bounds__(256) void mgemm_k(const ushort* __restrict__ A,
                                               const ushort* __restrict__ Bw,
                                               ushort* __restrict__ C,
                                               int N,
                                               const float* __restrict__ aux1,
                                               const float* __restrict__ aux2,
                                               float* __restrict__ hb) {
  __shared__ ushort As[64 * 64];
  __shared__ ushort Bs[64 * 64];
  int tid = threadIdx.x;
  int w = tid >> 6, lane = tid & 63;
  int c = lane & 15, g = lane >> 4;
  int wr = w >> 1, wc = w & 1;
  int lr = lane >> 3, lsl = lane & 7;

  const ushort* Ab = A + (size_t)(blockIdx.y * 64) * KT;
  const ushort* Bb = Bw + (size_t)(blockIdx.x * 64) * KT;

  f4 acc[2][2] = {};

  for (int kt = 0; kt < KT / 64; kt++) {
    if (kt) __syncthreads();
    // stage A,B tiles: linear LDS dest, source slot pre-XOR-swizzled
    #pragma unroll
    for (int j = 0; j < 2; j++) {
      int rl = j * 32 + w * 8 + lr;
      int slot = lsl ^ (rl & 7);
      async_copy16(&As[(j * 32 + w * 8) * 64], Ab + (size_t)rl * KT + kt * 64 + slot * 8);
      async_copy16(&Bs[(j * 32 + w * 8) * 64], Bb + (size_t)rl * KT + kt * 64 + slot * 8);
    }
    __syncthreads();   // drains vmcnt(0) + barrier
    #pragma unroll
    for (int ks2 = 0; ks2 < 2; ks2++) {
      short8 af[2], bf_[2];
      #pragma unroll
      for (int mi = 0; mi < 2; mi++) {
        int rowl = wr * 32 + mi * 16 + c;
        int slot = (ks2 * 4 + g) ^ (rowl & 7);
        af[mi] = *(const short8*)&As[rowl * 64 + slot * 8];
      }
      #pragma unroll
      for (int ni = 0; ni < 2; ni++) {
        int rowl = wc * 32 + ni * 16 + c;
        int slot = (ks2 * 4 + g) ^ (rowl & 7);
        bf_[ni] = *(const short8*)&Bs[rowl * 64 + slot * 8];
      }
      #pragma unroll
      for (int mi = 0; mi < 2; mi++)
        #pragma unroll
        for (int ni = 0; ni < 2; ni++)
          acc[mi][ni] = __builtin_amdgcn_mfma_f32_16x16x32_bf16(af[mi], bf_[ni], acc[mi][ni], 0, 0, 0);
    }
  }

  // epilogue: D element (mi,ni,r) -> row = m0+mi*16+4g+r, col = n0+ni*16+c
  int m0 = blockIdx.y * 64 + wr * 32;
  int n0 = blockIdx.x * 64 + wc * 32;
  #pragma unroll
  for (int mi = 0; mi < 2; mi++) {
    #pragma unroll
    for (int ni = 0; ni < 2; ni++) {
      #pragma unroll
      for (int r = 0; r < 4; r++) {
        int row = m0 + mi * 16 + 4 * g + r;
        int col = n0 + ni * 16 + c;
        float v = acc[mi][ni][r];
        if (EPI == 0 || EPI == 1) {
          int bI = row >> 10, dI = row & 1023;
          int hI = col >> 5, eI = col & 31;
          float o = (EPI == 1) ? v * aux1[row] * 0.17677669529663687f : v;
          C[(((size_t)(bI * HH + hI)) * DD + dI) * HDD + eI] = f2bf(o);
        } else if (EPI == 2) {
          int bI = row >> 10, dI = row & 1023;
          int hI = col >> 5, eI = col & 31;
          C[(((size_t)(bI * HH + hI)) * HDD + eI) * DD + dI] = f2bf(v);
        } else if (EPI == 3) {
          v += aux1[col];
          float gl = 0.5f * v * (1.0f + erff(v * 0.70710678118654752f));
          C[(size_t)row * N + col] = f2bf(gl);
        } else if (EPI == 4) {
          v += aux1[col];
          size_t idx = (size_t)row * EE + col;
          float nh = hb[idx] + aux2[col] * v;
          hb[idx] = nh;
          C[idx] = f2bf(nh);
        }
      }
    }
  }
}

// ---------------- MFMA flash attention v5: XCD-swizzled + static softmax + window cut ----------------
// Qbf,Kbf: bf16 [B,H,D,32] (Q pre-scaled by qscale/sqrt(32)); Vtb: bf16 [B,H,32,D].
// 1D grid of 1024; logical id swizzled so all 16 q-blocks of a (b,h) share an XCD
// (K/V panels stay L2-resident). Scores provably tiny (|qk|<<1, bias<=0) -> fixed
// softmax reference point m=0: no max tracking, no rescale, l-reduce once at end.
__global__ __launch_bounds__(256) void attn5_k(const ushort* __restrict__ Qbf,
                                               const ushort* __restrict__ Kbf,
                                               const ushort* __restrict__ Vtb,
                                               const float* __restrict__ gamma,
                                               const float* __restrict__ strength_p,
                                               float* __restrict__ h) {
  __shared__ __align__(16) ushort Pl[4][16][72];   // per-wave P tile, padded rows
  int tid = threadIdx.x;
  int w = tid >> 6, lane = tid & 63;
  int c = lane & 15, g = lane >> 4;
  // XCD-aware bijective swizzle: hw blocks {i : i%8==x} -> logical chunk x*128..
  int lid = (blockIdx.x & 7) * 128 + (blockIdx.x >> 3);
  int bh = lid >> 4;
  int diag = lid & 15;
  int b = bh >> 3, hh = bh & 7;
  int q0 = diag * 64 + w * 16;
  int qg = q0 + c;
  float ss = fmaxf(strength_p[0], 0.f) * exp2f(-(float)hh / 8.0f);
  const float L2E = 1.4426950408889634f;

  // Q fragment (B operand): lane holds Q[q0+c][8g..8g+7]
  short8 qf = *(const short8*)(Qbf + (((size_t)bh * DD + qg) << 5) + (g << 3));

  f4 oacc0 = {0.f, 0.f, 0.f, 0.f};
  f4 oacc1 = {0.f, 0.f, 0.f, 0.f};
  float lpart = 0.f;

  const ushort* Kb0 = Kbf + (((size_t)bh * DD + c) << 5) + (g << 3);
  const ushort* Vb0 = Vtb + ((size_t)(bh * HDD + c)) * DD + (g << 3);

  for (int kk = 0; kk < 16; kk++) {
    int ks = (diag + kk) & 15;
    if (kk) {
      // window cut: relative contribution bound < e^-14 -> negligible
      int dmin = (ks > diag) ? (ks * 64 - (q0 + 15)) : (q0 - (ks * 64 + 63));
      if (ss * (float)dmin > 14.0f) continue;
    }
    // ---- QK^T (swapped): 4 tiles of 16 keys, S^T[k][q], full K=32 contraction ----
    f4 sa[4];
    #pragma unroll
    for (int t = 0; t < 4; t++) {
      short8 kf = *(const short8*)(Kb0 + (((size_t)(ks * 64 + t * 16)) << 5));
      f4 z = {0.f, 0.f, 0.f, 0.f};
      sa[t] = __builtin_amdgcn_mfma_f32_16x16x32_bf16(kf, qf, z, 0, 0, 0);
    }
    // ---- bias (lane owns query col c; key = ks*64 + t*16 + 4g + r) ----
    float s[16];
    if (kk == 0) {
      #pragma unroll
      for (int t = 0; t < 4; t++) {
        #pragma unroll
        for (int r = 0; r < 4; r++) {
          int k = ks * 64 + t * 16 + 4 * g + r;
          float ad = fabsf((float)(qg - k));
          s[t * 4 + r] = (k == qg) ? -1e30f : fmaf(-ss, ad, sa[t][r]);
        }
      }
    } else {
      float sgn = (ks > diag) ? -ss : ss;   // bias = sgn*(k - qg), always <= 0
      int kb = ks * 64 + 4 * g - qg;
      #pragma unroll
      for (int t = 0; t < 4; t++) {
        #pragma unroll
        for (int r = 0; r < 4; r++) {
          float dk = (float)(kb + t * 16 + r);
          s[t * 4 + r] = fmaf(sgn, dk, sa[t][r]);
        }
      }
    }
    // ---- static-reference exp + per-lane partial sum + truncated bf16 pack ----
    #pragma unroll
    for (int i = 0; i < 16; i++) {
      float p = exp2f(s[i] * L2E);
      s[i] = p;
      lpart += p;
    }
    #pragma unroll
    for (int t = 0; t < 4; t++) {
      uint2 u;
      u.x = __builtin_amdgcn_perm(__float_as_uint(s[t * 4 + 1]), __float_as_uint(s[t * 4 + 0]), 0x07060302u);
      u.y = __builtin_amdgcn_perm(__float_as_uint(s[t * 4 + 3]), __float_as_uint(s[t * 4 + 2]), 0x07060302u);
      *(uint2*)&Pl[w][c][t * 16 + 4 * g] = u;
    }
    // ---- PV: O[q][e] += P[q][k] V[k][e], two K=32 halves, two e-tiles ----
    #pragma unroll
    for (int hb2 = 0; hb2 < 2; hb2++) {
      short8 pa = *(const short8*)&Pl[w][c][hb2 * 32 + 8 * g];
      short8 v0 = *(const short8*)(Vb0 + ks * 64 + hb2 * 32);
      short8 v1 = *(const short8*)(Vb0 + (size_t)16 * DD + ks * 64 + hb2 * 32);
      oacc0 = __builtin_amdgcn_mfma_f32_16x16x32_bf16(pa, v0, oacc0, 0, 0, 0);
      oacc1 = __builtin_amdgcn_mfma_f32_16x16x32_bf16(pa, v1, oacc1, 0, 0, 0);
    }
  }

  // ---- l reduce across the 4 lanes sharing query c (done once, not per step) ----
  lpart += __shfl_xor(lpart, 16);
  lpart += __shfl_xor(lpart, 32);
  float linv = 1.0f / lpart;

  // ---- epilogue: h += gamma * O / l ----
  #pragma unroll
  for (int r = 0; r < 4; r++) {
    float li = __shfl(linv, 4 * g + r);
    int q = q0 + 4 * g + r;
    size_t base = ((size_t)(b * DD + q)) * EE + hh * HDD;
    int e0 = c, e1 = 16 + c;
    h[base + e0] += gamma[hh * HDD + e0] * oacc0[r] * li;
    h[base + e1] += gamma[hh * HDD + e1] * oacc1[r] * li;
  }
}

// ---------------- LayerNorm over rows of 256 -> bf16 ----------------
__global__ __launch_bounds__(256) void ln_k(const float* __restrict__ hin,
                                            const float* __restrict__ w,
                                            const float* __restrict__ bb,
                                            ushort* __restrict__ y) {
  __shared__ float red[256];
  int r = blockIdx.x, t = threadIdx.x;
  float v = hin[(size_t)r * EE + t];
  red[t] = v; __syncthreads();
  for (int off = 128; off; off >>= 1) {
    if (t < off) red[t] += red[t + off];
    __syncthreads();
  }
  float mean = red[0] / (float)EE;
  __syncthreads();
  float dv = v - mean;
  red[t] = dv * dv; __syncthreads();
  for (int off = 128; off; off >>= 1) {
    if (t < off) red[t] += red[t + off];
    __syncthreads();
  }
  float var = red[0] / (float)EE;
  y[(size_t)r * EE + t] = f2bf(dv * rsqrtf(var + 1e-5f) * w[t] + bb[t]);
}

// ---------------- final projection to scalar per row ----------------
__global__ __launch_bounds__(256) void out_k(const ushort* __restrict__ t_,
                                             const float* __restrict__ w2,
                                             const float* __restrict__ b2,
                                             float* __restrict__ out) {
  int w = threadIdx.x >> 6, lane = threadIdx.x & 63;
  int r = blockIdx.x * 4 + w;
  float s = 0.f;
  #pragma unroll
  for (int i = 0; i < 4; i++) s += bf2f(t_[(size_t)r * EE + lane + i * 64]) * w2[lane + i * 64];
  #pragma unroll
  for (int off = 32; off; off >>= 1) s += __shfl_xor(s, off);
  if (lane == 0) out[r] = s + b2[0];
}

extern "C" void kernel_launch(void* const* d_in, const int* in_sizes, int n_in,
                              void* d_out, int out_size, void* d_ws, size_t ws_size,
                              hipStream_t stream) {
  const float* x            = (const float*)d_in[0];
  const float* value_w      = (const float*)d_in[1];
  const float* value_b      = (const float*)d_in[2];
  const float* feature_embed= (const float*)d_in[3];
  const float* binary_w     = (const float*)d_in[4];
  const float* qw           = (const float*)d_in[5];
  const float* kw           = (const float*)d_in[6];
  const float* vw           = (const float*)d_in[7];
  const float* film_alpha   = (const float*)d_in[8];
  const float* film_a       = (const float*)d_in[9];
  const float* ln1_w        = (const float*)d_in[10];
  const float* ln1_b        = (const float*)d_in[11];
  const float* ffn_w1       = (const float*)d_in[12];
  const float* ffn_b1       = (const float*)d_in[13];
  const float* ffn_w2       = (const float*)d_in[14];
  const float* ffn_b2       = (const float*)d_in[15];
  const float* gamma_attn   = (const float*)d_in[16];
  const float* gamma_ffn    = (const float*)d_in[17];
  const float* corr_ln_w    = (const float*)d_in[18];
  const float* corr_ln_b    = (const float*)d_in[19];
  const float* corr_w1      = (const float*)d_in[20];
  const float* corr_b1      = (const float*)d_in[21];
  const float* corr_w2      = (const float*)d_in[22];
  const float* corr_b2      = (const float*)d_in[23];
  const float* alibi_strength=(const float*)d_in[24];

  const size_t ME = (size_t)BD * DD * EE;   // 2M
  float* ws = (float*)d_ws;
  float* pos    = ws;                       // 262144 f
  float* qscale = pos + DD * EE;            // 8192 f
  float* hb     = qscale + BD * DD;         // 2M f
  ushort* kv_bf = (ushort*)(hb + ME);       // 2M us
  ushort* hb_bf = kv_bf + ME;               // 2M us
  ushort* yb_bf = hb_bf + ME;               // 2M us
  ushort* tb_bf = yb_bf + ME;               // 4M us
  ushort* Qbf   = tb_bf + 2 * ME;           // 2M us
  ushort* Kbf   = Qbf + ME;                 // 2M us
  ushort* Vtb   = Kbf + ME;                 // 2M us
  ushort* wbf   = Vtb + ME;                 // 524288 us
  ushort* qwb   = wbf;
  ushort* kwb   = wbf + 65536;
  ushort* vwb   = wbf + 131072;
  ushort* w1b   = wbf + 196608;
  ushort* w2b   = wbf + 327680;
  ushort* cw1b  = wbf + 458752;

  const int M = BD * DD;   // 8192

  k_qscale<<<BD, 256, 0, stream>>>(x, film_alpha, film_a, qscale);
  k_pos<<<DD, 256, 0, stream>>>(feature_embed, binary_w, pos);
  k_kvh<<<(BD * DD * EE) / 256, 256, 0, stream>>>(x, value_w, value_b, pos, kv_bf, hb, hb_bf);
  k_wconv<<<524288 / 256, 256, 0, stream>>>(qw, kw, vw, ffn_w1, ffn_w2, corr_w1, wbf);

  mgemm_k<0, 256><<<dim3(EE / 64, M / 64), 256, 0, stream>>>(kv_bf, kwb, Kbf, EE, nullptr, nullptr, nullptr);
  mgemm_k<2, 256><<<dim3(EE / 64, M / 64), 256, 0, stream>>>(kv_bf, vwb, Vtb, EE, nullptr, nullptr, nullptr);

  for (int layer = 0; layer < 2; layer++) {
    mgemm_k<1, 256><<<dim3(EE / 64, M / 64), 256, 0, stream>>>(hb_bf, qwb, Qbf, EE, qscale, nullptr, nullptr);
    attn5_k<<<dim3(BD * HH * (DD / 64)), 256, 0, stream>>>(Qbf, Kbf, Vtb, gamma_attn, alibi_strength, hb);
    ln_k<<<M, 256, 0, stream>>>(hb, ln1_w, ln1_b, yb_bf);
    mgemm_k<3, 256><<<dim3((2 * EE) / 64, M / 64), 256, 0, stream>>>(yb_bf, w1b, tb_bf, 2 * EE, ffn_b1, nullptr, nullptr);
    mgemm_k<4, 512><<<dim3(EE / 64, M / 64), 256, 0, stream>>>(tb_bf, w2b, hb_bf, EE, ffn_b2, gamma_ffn, hb);
  }

  ln_k<<<M, 256, 0, stream>>>(hb, corr_ln_w, corr_ln_b, yb_bf);
  mgemm_k<3, 256><<<dim3(EE / 64, M / 64), 256, 0, stream>>>(yb_bf, cw1b, tb_bf, EE, corr_b1, nullptr, nullptr);
  out_k<<<M / 4, 256, 0, stream>>>(tb_bf, corr_w2, corr_b2, (float*)d_out);
}